// Round 1
// 186.992 us; speedup vs baseline: 1.0864x; 1.0864x over previous
//
#include <hip/hip_runtime.h>
#include <math.h>

#define L 256
#define E 128
#define H 4
#define C 32
#define P (L*L)  // 65536

typedef __bf16 bf16;
typedef __bf16 bf16x8 __attribute__((ext_vector_type(8)));
typedef __bf16 bf16x4 __attribute__((ext_vector_type(4)));
typedef float  f32x4  __attribute__((ext_vector_type(4)));

#define MFMA(a,b,c) __builtin_amdgcn_mfma_f32_16x16x32_bf16((a),(b),(c),0,0,0)

// ---------------------------------------------------------------------------
// k_prep: emit weights in MFMA A-fragment order so every A-frag load is one
// coalesced 16B/lane transaction. frag f=mt*4+kt; elem j at lane (g,l15) is
// A[row=16mt+l15][k=32kt+8g+j] = W[k][row] (*C^-0.5 for Wq).
// WbF: rows 0..3 = Wb columns, rows 4..15 zero.
// ---------------------------------------------------------------------------
__global__ __launch_bounds__(256) void k_prep(
    const float* __restrict__ Wq, const float* __restrict__ Wk,
    const float* __restrict__ Wv, const float* __restrict__ Wfu,
    const float* __restrict__ Wo, const float* __restrict__ Wb,
    bf16* __restrict__ WF, bf16* __restrict__ WoF, bf16* __restrict__ WbF)
{
  const int m = blockIdx.x;  // 0..5
  const int lane = threadIdx.x & 63, wv = threadIdx.x >> 6;
  const int g = lane >> 4, l15 = lane & 15;
  if (m < 5) {
    const float* W = (m==0)?Wq:(m==1)?Wk:(m==2)?Wv:(m==3)?Wfu:Wo;
    bf16* dst = (m < 4) ? (WF + (size_t)m * 16384) : WoF;
    const float sc = (m == 0) ? 0.17677669529663689f : 1.0f;
    for (int f = wv; f < 32; f += 4) {
      const int mt = f >> 2, kt = f & 3;
      const int row = 16*mt + l15, k0 = 32*kt + 8*g;
      bf16x8 o;
      #pragma unroll
      for (int j = 0; j < 8; ++j) o[j] = (bf16)(W[(size_t)(k0+j)*128 + row] * sc);
      *(bf16x8*)(dst + ((size_t)f*64 + lane)*8) = o;
    }
  } else {
    const int kt = wv, k0 = 32*kt + 8*g;
    bf16x8 o;
    #pragma unroll
    for (int j = 0; j < 8; ++j)
      o[j] = (l15 < 4) ? (bf16)Wb[(size_t)(k0+j)*4 + l15] : (bf16)0.0f;
    *(bf16x8*)(WbF + ((size_t)kt*64 + lane)*8) = o;
  }
}

// ---------------------------------------------------------------------------
// k_ln_proj: LN -> bf16 x in LDS; per-wave matrix (q,k,v,gate) via MFMA with
// fragment-ordered A loads; pair_bias via MFMA (wave w does positions 16w..).
// Epilogue staged through LDS -> fully coalesced global stores.
// q,k,v head-major [h][P][32]; gate [P][128]; pb [P][4] fp32.
// ---------------------------------------------------------------------------
__global__ __launch_bounds__(256) void k_ln_proj(
    const float* __restrict__ pr, const float* __restrict__ gamma,
    const float* __restrict__ beta, const float* __restrict__ bfu,
    const bf16* __restrict__ WF, const bf16* __restrict__ WbF,
    bf16* __restrict__ qbh, bf16* __restrict__ kbh, bf16* __restrict__ vbh,
    bf16* __restrict__ gfb, float* __restrict__ pbo)
{
  __shared__ bf16 xs[64 * 136];        // 17.0 KB
  __shared__ bf16 stag[4][16 * 136];   // 17.0 KB
  const int tid = threadIdx.x;
  const int base = blockIdx.x * 64;

  // --- LayerNorm (4 threads per position) ---
  {
    const int pl = tid >> 2, sub = tid & 3;
    const float4* src = (const float4*)(pr + (size_t)(base + pl) * 128 + sub * 32);
    float4 r[8];
    float s = 0.f, ss = 0.f;
    #pragma unroll
    for (int j = 0; j < 8; ++j) {
      r[j] = src[j];
      s  += r[j].x + r[j].y + r[j].z + r[j].w;
      ss += r[j].x*r[j].x + r[j].y*r[j].y + r[j].z*r[j].z + r[j].w*r[j].w;
    }
    s  += __shfl_xor(s, 1, 4);  s  += __shfl_xor(s, 2, 4);
    ss += __shfl_xor(ss, 1, 4); ss += __shfl_xor(ss, 2, 4);
    const float mu   = s * 0.0078125f;
    const float var  = ss * 0.0078125f - mu * mu;
    const float rstd = rsqrtf(var + 1e-5f);
    const float4* g4 = (const float4*)(gamma + sub * 32);
    const float4* b4 = (const float4*)(beta + sub * 32);
    bf16* xr = xs + pl * 136 + sub * 32;
    #pragma unroll
    for (int i = 0; i < 4; ++i) {
      float4 r0 = r[2*i], r1 = r[2*i+1];
      float4 gg0 = g4[2*i], gg1 = g4[2*i+1], bb0 = b4[2*i], bb1 = b4[2*i+1];
      bf16x8 o;
      o[0] = (bf16)((r0.x - mu) * rstd * gg0.x + bb0.x);
      o[1] = (bf16)((r0.y - mu) * rstd * gg0.y + bb0.y);
      o[2] = (bf16)((r0.z - mu) * rstd * gg0.z + bb0.z);
      o[3] = (bf16)((r0.w - mu) * rstd * gg0.w + bb0.w);
      o[4] = (bf16)((r1.x - mu) * rstd * gg1.x + bb1.x);
      o[5] = (bf16)((r1.y - mu) * rstd * gg1.y + bb1.y);
      o[6] = (bf16)((r1.z - mu) * rstd * gg1.z + bb1.z);
      o[7] = (bf16)((r1.w - mu) * rstd * gg1.w + bb1.w);
      *(bf16x8*)(xr + 8 * i) = o;
    }
  }
  __syncthreads();

  const int w = tid >> 6, lane = tid & 63, g = lane >> 4, l15 = lane & 15;
  const f32x4 z = {0.f, 0.f, 0.f, 0.f};

  // --- pair_bias via MFMA: wave w covers positions base+16w..base+16w+15 ---
  {
    f32x4 acc = z;
    #pragma unroll
    for (int kt = 0; kt < 4; ++kt) {
      bf16x8 a = *(const bf16x8*)(WbF + ((size_t)kt*64 + lane)*8);
      bf16x8 b = *(const bf16x8*)(xs + (16*w + l15)*136 + 32*kt + 8*g);
      acc = MFMA(a, b, acc);
    }
    if (g == 0)
      *(float4*)(pbo + (size_t)(base + 16*w + l15)*4) =
          make_float4(acc[0], acc[1], acc[2], acc[3]);
  }

  // --- projection: wave w -> matrix w ---
  const bf16* WFw = WF + (size_t)w * 16384;
  bf16* stw = stag[w];

  for (int nt = 0; nt < 4; ++nt) {
    bf16x8 bfr[4];
    #pragma unroll
    for (int kt = 0; kt < 4; ++kt)
      bfr[kt] = *(const bf16x8*)(xs + (16*nt + l15)*136 + 32*kt + 8*g);
    f32x4 acc[8];
    #pragma unroll
    for (int mt = 0; mt < 8; ++mt) acc[mt] = z;
    #pragma unroll
    for (int kt = 0; kt < 4; ++kt)
      #pragma unroll
      for (int mt = 0; mt < 8; ++mt) {
        bf16x8 a = *(const bf16x8*)(WFw + ((size_t)(mt*4 + kt)*64 + lane)*8);
        acc[mt] = MFMA(a, bfr[kt], acc[mt]);
      }

    // epilogue -> LDS staging (D: col=16mt+4g+r, pos=l15)
    #pragma unroll
    for (int mt = 0; mt < 8; ++mt) {
      const int col = 16*mt + 4*g;
      f32x4 vv = acc[mt];
      if (w == 3) {
        float4 bb = *(const float4*)(bfu + col);
        vv[0] = 1.f / (1.f + __expf(-(vv[0] + bb.x)));
        vv[1] = 1.f / (1.f + __expf(-(vv[1] + bb.y)));
        vv[2] = 1.f / (1.f + __expf(-(vv[2] + bb.z)));
        vv[3] = 1.f / (1.f + __expf(-(vv[3] + bb.w)));
      }
      bf16x4 o;
      o[0] = (bf16)vv[0]; o[1] = (bf16)vv[1]; o[2] = (bf16)vv[2]; o[3] = (bf16)vv[3];
      *(bf16x4*)(stw + l15*136 + col) = o;
    }

    // coalesced global store (same-wave LDS ordering guarantees visibility)
    #pragma unroll
    for (int i = 0; i < 4; ++i) {
      const int flat = i*512 + lane*8;
      const int p = flat >> 7, c = flat & 127;
      bf16x8 val = *(const bf16x8*)(stw + p*136 + c);
      if (w == 3) {
        *(bf16x8*)(gfb + ((size_t)(base + 16*nt + p))*128 + c) = val;
      } else {
        bf16* dst = (w == 0) ? qbh : (w == 1) ? kbh : vbh;
        const int h = c >> 5;
        *(bf16x8*)(dst + ((size_t)h*P + base + 16*nt + p)*32 + (c & 31)) = val;
      }
    }
  }
}

// ---------------------------------------------------------------------------
// k_bias: T5[h][q][v] = mask[q,v] + pb[q,v,h]  (bf16). grid 256 (q), 256 thr.
// float4 read of pb (coalesced), 4 scalar bf16 writes -> 4 contiguous planes.
// ---------------------------------------------------------------------------
__global__ __launch_bounds__(256) void k_bias(
    const float* __restrict__ mask, const float* __restrict__ pb,
    bf16* __restrict__ T5)
{
  const int q = blockIdx.x;
  const int v = threadIdx.x;
  const size_t qv = (size_t)q*256 + v;
  const float m = mask[qv];
  float4 p = *(const float4*)(pb + qv*4);
  T5[qv]            = (bf16)(m + p.x);
  T5[qv +   65536]  = (bf16)(m + p.y);
  T5[qv + 2*65536]  = (bf16)(m + p.z);
  T5[qv + 3*65536]  = (bf16)(m + p.w);
}

// ---------------------------------------------------------------------------
// k_attn: block=(s,h), 4 waves x 64 q-rows.
// Swapped QK^T orientation: A = q-proj (v axis on MFMA rows), B = k-proj row
// (q axis on MFMA cols = l15). Staging permutes v->slot sigma(v) so QK tile
// t=2kt+half yields scores at v=32kt+4half+8g+r -> the PV B-fragment for kt is
// pack(exp(sc[2kt]), exp(sc[2kt+1])) entirely lane-local: NO LDS round-trip
// for P. Softmax: per-lane accum + 2 shfl_xor; PV runs on unnormalized exp,
// output divided by row-sum. vT is XOR-swizzled (col ^ (row>>3)<<5) to kill
// the transpose-build bank conflicts.
// ---------------------------------------------------------------------------
__global__ __launch_bounds__(256) void k_attn(
    const bf16* __restrict__ qbh, const bf16* __restrict__ kbh,
    const bf16* __restrict__ vbh, const bf16* __restrict__ T5,
    bf16* __restrict__ aob)
{
  __shared__ bf16 qs[256 * 40];   // 20.0 KB, slot-permuted q-projection
  __shared__ bf16 vT[32 * 264];   // 16.5 KB, swizzled V^T
  const int tid = threadIdx.x;
  const int s = blockIdx.x >> 2, h = blockIdx.x & 3;
  const int rb = s * 256;
  const bf16* qh = qbh + (size_t)h * P * 32;
  const bf16* kh = kbh + (size_t)h * P * 32;
  const bf16* vh = vbh + (size_t)h * P * 32;
  const bf16* T5h = T5 + (size_t)h * 65536;

  // stage q (slot-permuted rows, stride 40) and vT (swizzled transpose)
  #pragma unroll
  for (int i = 0; i < 4; ++i) {
    const int flat = i*2048 + tid*8;
    const int pos = flat >> 5, cc = flat & 31;
    // sigma: pos bits [7:5]=kt [4:3]=c2 [2]=half [1:0]=m -> slot bits
    //        [7:5]=kt [4]=half [3:2]=c2 [1:0]=m   (bijective bit swap)
    const int slot = (pos & 0xE3) | ((pos & 0x04) << 2) | ((pos & 0x18) >> 1);
    bf16x8 qv = *(const bf16x8*)(qh + ((size_t)rb + pos)*32 + cc);
    *(bf16x8*)(qs + slot*40 + cc) = qv;
    bf16x8 vv = *(const bf16x8*)(vh + ((size_t)rb + pos)*32 + cc);
    #pragma unroll
    for (int j = 0; j < 8; ++j) {
      const int row = cc + j;
      vT[row*264 + (pos ^ ((row >> 3) << 5))] = vv[j];
    }
  }
  __syncthreads();

  const int w = tid >> 6, lane = tid & 63, g = lane >> 4, l15 = lane & 15;

  // hoist PV A-fragments from swizzled vT (once per block)
  bf16x8 av[2][8];
  #pragma unroll
  for (int mt = 0; mt < 2; ++mt) {
    const int row = 16*mt + l15;
    const int X = (row >> 3) << 5;
    #pragma unroll
    for (int kt = 0; kt < 8; ++kt)
      av[mt][kt] = *(const bf16x8*)(vT + row*264 + ((32*kt + 8*g) ^ X));
  }

  bf16* aoh = aob + (size_t)h * P * 32;
  const f32x4 z = {0.f, 0.f, 0.f, 0.f};

  for (int qt = 0; qt < 4; ++qt) {
    const int q = w*64 + qt*16 + l15;
    // B-frag: k-projection row q (carries the softmax's q index on cols)
    bf16x8 bq = *(const bf16x8*)(kh + ((size_t)rb + q)*32 + 8*g);
    const bf16* Trow = T5h + (size_t)q * 256 + 8*g;
    f32x4 o0 = z, o1 = z;
    float rs = 0.f;
    #pragma unroll
    for (int kt = 0; kt < 8; ++kt) {
      bf16x8 a0 = *(const bf16x8*)(qs + (16*(2*kt + 0) + l15)*40 + 8*g);
      bf16x8 a1 = *(const bf16x8*)(qs + (16*(2*kt + 1) + l15)*40 + 8*g);
      f32x4 s0 = MFMA(a0, bq, z);
      f32x4 s1 = MFMA(a1, bq, z);
      bf16x4 b0 = *(const bf16x4*)(Trow + 32*kt);
      bf16x4 b1 = *(const bf16x4*)(Trow + 32*kt + 4);
      bf16x8 pf;
      #pragma unroll
      for (int r = 0; r < 4; ++r) {
        float e0 = __expf(s0[r] + (float)b0[r]);
        float e1 = __expf(s1[r] + (float)b1[r]);
        pf[r]     = (bf16)e0;
        pf[4 + r] = (bf16)e1;
        rs += (float)pf[r] + (float)pf[4 + r];  // sum the rounded weights
      }
      o0 = MFMA(av[0][kt], pf, o0);
      o1 = MFMA(av[1][kt], pf, o1);
    }
    rs += __shfl_xor(rs, 16);
    rs += __shfl_xor(rs, 32);
    const float inv = 1.f / rs;
    bf16x4 p0, p1;
    #pragma unroll
    for (int r = 0; r < 4; ++r) {
      p0[r] = (bf16)(o0[r] * inv);
      p1[r] = (bf16)(o1[r] * inv);
    }
    bf16* dst = aoh + ((size_t)rb + q)*32;
    *(bf16x4*)(dst + 4*g)      = p0;
    *(bf16x4*)(dst + 16 + 4*g) = p1;
  }
}

// ---------------------------------------------------------------------------
// k_gate_out: out = (ao * gate) @ Wo + bo via MFMA; WoF fragment-ordered.
// ---------------------------------------------------------------------------
__global__ __launch_bounds__(256) void k_gate_out(
    const bf16* __restrict__ aob, const bf16* __restrict__ gfb,
    const bf16* __restrict__ WoF, const float* __restrict__ bo,
    float* __restrict__ out)
{
  __shared__ bf16 gs[64 * 136];
  const int tid = threadIdx.x;
  const int base = blockIdx.x * 64;

  #pragma unroll
  for (int i = 0; i < 4; ++i) {
    const int flat = i*2048 + tid*8;
    const int pos = flat >> 7, c = flat & 127, h = c >> 5;
    bf16x8 a = *(const bf16x8*)(aob + ((size_t)h*P + base + pos)*32 + (c & 31));
    bf16x8 f = *(const bf16x8*)(gfb + ((size_t)(base + pos))*128 + c);
    bf16x8 o;
    #pragma unroll
    for (int j = 0; j < 8; ++j) o[j] = (bf16)((float)a[j] * (float)f[j]);
    *(bf16x8*)(gs + pos*136 + c) = o;
  }
  __syncthreads();

  const int w = tid >> 6, lane = tid & 63, g = lane >> 4, l15 = lane & 15;
  const f32x4 z = {0.f, 0.f, 0.f, 0.f};

  for (int nt = 0; nt < 4; ++nt) {
    bf16x8 bfr[4];
    #pragma unroll
    for (int kt = 0; kt < 4; ++kt)
      bfr[kt] = *(const bf16x8*)(gs + (16*nt + l15)*136 + 32*kt + 8*g);
    f32x4 a0 = z, a1 = z;
    #pragma unroll
    for (int kt = 0; kt < 4; ++kt) {
      bf16x8 af0 = *(const bf16x8*)(WoF + ((size_t)((2*w+0)*4 + kt)*64 + lane)*8);
      bf16x8 af1 = *(const bf16x8*)(WoF + ((size_t)((2*w+1)*4 + kt)*64 + lane)*8);
      a0 = MFMA(af0, bfr[kt], a0);
      a1 = MFMA(af1, bfr[kt], a1);
    }
    const int pos = base + 16*nt + l15;
    {
      const int col = 16*(2*w + 0) + 4*g;
      float4 bb = *(const float4*)(bo + col);
      *(float4*)(out + (size_t)pos*128 + col) =
          make_float4(a0[0] + bb.x, a0[1] + bb.y, a0[2] + bb.z, a0[3] + bb.w);
    }
    {
      const int col = 16*(2*w + 1) + 4*g;
      float4 bb = *(const float4*)(bo + col);
      *(float4*)(out + (size_t)pos*128 + col) =
          make_float4(a1[0] + bb.x, a1[1] + bb.y, a1[2] + bb.z, a1[3] + bb.w);
    }
  }
}

// ---------------------------------------------------------------------------
extern "C" void kernel_launch(void* const* d_in, const int* in_sizes, int n_in,
                              void* d_out, int out_size, void* d_ws, size_t ws_size,
                              hipStream_t stream) {
  const float* pr    = (const float*)d_in[0];
  const float* mask  = (const float*)d_in[1];
  const float* gamma = (const float*)d_in[2];
  const float* beta  = (const float*)d_in[3];
  const float* Wq    = (const float*)d_in[4];
  const float* Wk    = (const float*)d_in[5];
  const float* Wv    = (const float*)d_in[6];
  const float* Wb    = (const float*)d_in[7];
  const float* Wfu   = (const float*)d_in[8];
  const float* bfu   = (const float*)d_in[9];
  const float* Wo    = (const float*)d_in[10];
  const float* bo    = (const float*)d_in[11];
  float* out = (float*)d_out;

  bf16* qbh = (bf16*)d_ws;                        // H*P*32
  bf16* kbh = qbh + (size_t)H * P * 32;
  bf16* vbh = kbh + (size_t)H * P * 32;
  bf16* gfb = vbh + (size_t)H * P * 32;           // P*128
  bf16* aob = gfb + (size_t)P * 128;              // H*P*32
  bf16* T5  = aob + (size_t)H * P * 32;           // H*65536 = H*P
  bf16* WF  = T5  + (size_t)H * P;                // 4*16384
  bf16* WoF = WF  + 4 * 16384;                    // 16384
  bf16* WbF = WoF + 16384;                        // 2048
  float* pb = (float*)(WbF + 2048);               // P*4 fp32

  k_prep<<<6, 256, 0, stream>>>(Wq, Wk, Wv, Wfu, Wo, Wb, WF, WoF, WbF);
  k_ln_proj<<<1024, 256, 0, stream>>>(pr, gamma, beta, bfu, WF, WbF,
                                      qbh, kbh, vbh, gfb, pb);
  k_bias<<<256, 256, 0, stream>>>(mask, pb, T5);
  k_attn<<<1024, 256, 0, stream>>>(qbh, kbh, vbh, T5, aob);
  k_gate_out<<<1024, 256, 0, stream>>>(aob, gfb, WoF, bo, out);
}

// Round 2
// 183.793 us; speedup vs baseline: 1.1053x; 1.0174x over previous
//
#include <hip/hip_runtime.h>
#include <math.h>

#define L 256
#define E 128
#define H 4
#define C 32
#define P (L*L)  // 65536

typedef __bf16 bf16;
typedef __bf16 bf16x8 __attribute__((ext_vector_type(8)));
typedef __bf16 bf16x4 __attribute__((ext_vector_type(4)));
typedef float  f32x4  __attribute__((ext_vector_type(4)));

#define MFMA(a,b,c) __builtin_amdgcn_mfma_f32_16x16x32_bf16((a),(b),(c),0,0,0)

// ---------------------------------------------------------------------------
// k_prep: emit weights in MFMA A-fragment order. Grid 41: blocks 0..39 cover
// (m, frag-quad) with one fragment per wave (41x more parallelism than the
// old 6-block version); block 40 builds WbF.
// frag f=mt*4+kt; elem j at lane (g,l15) is A[row=16mt+l15][k=32kt+8g+j]
// = W[k][row] (*C^-0.5 for Wq). WbF: rows 0..3 = Wb columns, rows 4..15 zero.
// ---------------------------------------------------------------------------
__global__ __launch_bounds__(256) void k_prep(
    const float* __restrict__ Wq, const float* __restrict__ Wk,
    const float* __restrict__ Wv, const float* __restrict__ Wfu,
    const float* __restrict__ Wo, const float* __restrict__ Wb,
    bf16* __restrict__ WF, bf16* __restrict__ WoF, bf16* __restrict__ WbF)
{
  const int b = blockIdx.x;  // 0..40
  const int lane = threadIdx.x & 63, wv = threadIdx.x >> 6;
  const int g = lane >> 4, l15 = lane & 15;
  if (b < 40) {
    const int m = b >> 3;
    const int f = (b & 7) * 4 + wv;
    const float* W = (m==0)?Wq:(m==1)?Wk:(m==2)?Wv:(m==3)?Wfu:Wo;
    bf16* dst = (m < 4) ? (WF + (size_t)m * 16384) : WoF;
    const float sc = (m == 0) ? 0.17677669529663689f : 1.0f;
    const int mt = f >> 2, kt = f & 3;
    const int row = 16*mt + l15, k0 = 32*kt + 8*g;
    bf16x8 o;
    #pragma unroll
    for (int j = 0; j < 8; ++j) o[j] = (bf16)(W[(size_t)(k0+j)*128 + row] * sc);
    *(bf16x8*)(dst + ((size_t)f*64 + lane)*8) = o;
  } else {
    const int kt = wv, k0 = 32*kt + 8*g;
    bf16x8 o;
    #pragma unroll
    for (int j = 0; j < 8; ++j)
      o[j] = (l15 < 4) ? (bf16)Wb[(size_t)(k0+j)*4 + l15] : (bf16)0.0f;
    *(bf16x8*)(WbF + ((size_t)kt*64 + lane)*8) = o;
  }
}

// ---------------------------------------------------------------------------
// k_ln_proj: LN -> bf16 x in LDS; per-wave matrix (q,k,v,gate) via MFMA.
// NEW: all 32 weight A-fragments are hoisted into VGPRs (128 regs) and the
// loads are issued BEFORE __syncthreads so their L2 latency hides under the
// LN barrier wait; the nt loop is then pure LDS-read + MFMA (removes the 4x
// per-nt global weight reload = 512 KB L2 traffic/block).
// q,k,v head-major [h][P][32]; gate [P][128]; pb [P][4] fp32.
// ---------------------------------------------------------------------------
__global__ __launch_bounds__(256) void k_ln_proj(
    const float* __restrict__ pr, const float* __restrict__ gamma,
    const float* __restrict__ beta, const float* __restrict__ bfu,
    const bf16* __restrict__ WF, const bf16* __restrict__ WbF,
    bf16* __restrict__ qbh, bf16* __restrict__ kbh, bf16* __restrict__ vbh,
    bf16* __restrict__ gfb, float* __restrict__ pbo)
{
  __shared__ bf16 xs[64 * 136];        // 17.0 KB
  __shared__ bf16 stag[4][16 * 136];   // 17.0 KB
  const int tid = threadIdx.x;
  const int base = blockIdx.x * 64;
  const int w = tid >> 6, lane = tid & 63, g = lane >> 4, l15 = lane & 15;

  // --- LayerNorm (4 threads per position) ---
  {
    const int pl = tid >> 2, sub = tid & 3;
    const float4* src = (const float4*)(pr + (size_t)(base + pl) * 128 + sub * 32);
    float4 r[8];
    float s = 0.f, ss = 0.f;
    #pragma unroll
    for (int j = 0; j < 8; ++j) {
      r[j] = src[j];
      s  += r[j].x + r[j].y + r[j].z + r[j].w;
      ss += r[j].x*r[j].x + r[j].y*r[j].y + r[j].z*r[j].z + r[j].w*r[j].w;
    }
    s  += __shfl_xor(s, 1, 4);  s  += __shfl_xor(s, 2, 4);
    ss += __shfl_xor(ss, 1, 4); ss += __shfl_xor(ss, 2, 4);
    const float mu   = s * 0.0078125f;
    const float var  = ss * 0.0078125f - mu * mu;
    const float rstd = rsqrtf(var + 1e-5f);
    const float4* g4 = (const float4*)(gamma + sub * 32);
    const float4* b4 = (const float4*)(beta + sub * 32);
    bf16* xr = xs + pl * 136 + sub * 32;
    #pragma unroll
    for (int i = 0; i < 4; ++i) {
      float4 r0 = r[2*i], r1 = r[2*i+1];
      float4 gg0 = g4[2*i], gg1 = g4[2*i+1], bb0 = b4[2*i], bb1 = b4[2*i+1];
      bf16x8 o;
      o[0] = (bf16)((r0.x - mu) * rstd * gg0.x + bb0.x);
      o[1] = (bf16)((r0.y - mu) * rstd * gg0.y + bb0.y);
      o[2] = (bf16)((r0.z - mu) * rstd * gg0.z + bb0.z);
      o[3] = (bf16)((r0.w - mu) * rstd * gg0.w + bb0.w);
      o[4] = (bf16)((r1.x - mu) * rstd * gg1.x + bb1.x);
      o[5] = (bf16)((r1.y - mu) * rstd * gg1.y + bb1.y);
      o[6] = (bf16)((r1.z - mu) * rstd * gg1.z + bb1.z);
      o[7] = (bf16)((r1.w - mu) * rstd * gg1.w + bb1.w);
      *(bf16x8*)(xr + 8 * i) = o;
    }
  }

  // --- hoist this wave's 32 weight A-fragments (issued pre-barrier so the
  //     L2 latency overlaps the barrier wait) ---
  const bf16* WFw = WF + (size_t)w * 16384;
  bf16x8 af[32];
  #pragma unroll
  for (int f = 0; f < 32; ++f)
    af[f] = *(const bf16x8*)(WFw + ((size_t)f*64 + lane)*8);

  __syncthreads();

  const f32x4 z = {0.f, 0.f, 0.f, 0.f};

  // --- pair_bias via MFMA: wave w covers positions base+16w..base+16w+15 ---
  {
    f32x4 acc = z;
    #pragma unroll
    for (int kt = 0; kt < 4; ++kt) {
      bf16x8 a = *(const bf16x8*)(WbF + ((size_t)kt*64 + lane)*8);
      bf16x8 b = *(const bf16x8*)(xs + (16*w + l15)*136 + 32*kt + 8*g);
      acc = MFMA(a, b, acc);
    }
    if (g == 0)
      *(float4*)(pbo + (size_t)(base + 16*w + l15)*4) =
          make_float4(acc[0], acc[1], acc[2], acc[3]);
  }

  // --- projection: wave w -> matrix w ---
  bf16* stw = stag[w];

  for (int nt = 0; nt < 4; ++nt) {
    bf16x8 bfr[4];
    #pragma unroll
    for (int kt = 0; kt < 4; ++kt)
      bfr[kt] = *(const bf16x8*)(xs + (16*nt + l15)*136 + 32*kt + 8*g);
    f32x4 acc[8];
    #pragma unroll
    for (int mt = 0; mt < 8; ++mt) acc[mt] = z;
    #pragma unroll
    for (int kt = 0; kt < 4; ++kt)
      #pragma unroll
      for (int mt = 0; mt < 8; ++mt)
        acc[mt] = MFMA(af[mt*4 + kt], bfr[kt], acc[mt]);

    // epilogue -> LDS staging (D: col=16mt+4g+r, pos=l15)
    #pragma unroll
    for (int mt = 0; mt < 8; ++mt) {
      const int col = 16*mt + 4*g;
      f32x4 vv = acc[mt];
      if (w == 3) {
        float4 bb = *(const float4*)(bfu + col);
        vv[0] = 1.f / (1.f + __expf(-(vv[0] + bb.x)));
        vv[1] = 1.f / (1.f + __expf(-(vv[1] + bb.y)));
        vv[2] = 1.f / (1.f + __expf(-(vv[2] + bb.z)));
        vv[3] = 1.f / (1.f + __expf(-(vv[3] + bb.w)));
      }
      bf16x4 o;
      o[0] = (bf16)vv[0]; o[1] = (bf16)vv[1]; o[2] = (bf16)vv[2]; o[3] = (bf16)vv[3];
      *(bf16x4*)(stw + l15*136 + col) = o;
    }

    // coalesced global store (same-wave LDS ordering guarantees visibility)
    #pragma unroll
    for (int i = 0; i < 4; ++i) {
      const int flat = i*512 + lane*8;
      const int p = flat >> 7, c = flat & 127;
      bf16x8 val = *(const bf16x8*)(stw + p*136 + c);
      if (w == 3) {
        *(bf16x8*)(gfb + ((size_t)(base + 16*nt + p))*128 + c) = val;
      } else {
        bf16* dst = (w == 0) ? qbh : (w == 1) ? kbh : vbh;
        const int h = c >> 5;
        *(bf16x8*)(dst + ((size_t)h*P + base + 16*nt + p)*32 + (c & 31)) = val;
      }
    }
  }
}

// ---------------------------------------------------------------------------
// k_bias: T5[h][q][v] = mask[q,v] + pb[q,v,h]  (bf16). grid 256 (q), 256 thr.
// float4 read of pb (coalesced), 4 scalar bf16 writes -> 4 contiguous planes.
// ---------------------------------------------------------------------------
__global__ __launch_bounds__(256) void k_bias(
    const float* __restrict__ mask, const float* __restrict__ pb,
    bf16* __restrict__ T5)
{
  const int q = blockIdx.x;
  const int v = threadIdx.x;
  const size_t qv = (size_t)q*256 + v;
  const float m = mask[qv];
  float4 p = *(const float4*)(pb + qv*4);
  T5[qv]            = (bf16)(m + p.x);
  T5[qv +   65536]  = (bf16)(m + p.y);
  T5[qv + 2*65536]  = (bf16)(m + p.z);
  T5[qv + 3*65536]  = (bf16)(m + p.w);
}

// ---------------------------------------------------------------------------
// k_attn: block=(s,h), 4 waves x 64 q-rows.
// Swapped QK^T orientation: A = q-proj (v axis on MFMA rows), B = k-proj row
// (q axis on MFMA cols = l15). Staging permutes v->slot sigma(v) so QK tile
// t=2kt+half yields scores at v=32kt+4half+8g+r -> the PV B-fragment for kt is
// pack(exp(sc[2kt]), exp(sc[2kt+1])) entirely lane-local: NO LDS round-trip
// for P. Softmax: per-lane accum + 2 shfl_xor; PV runs on unnormalized exp,
// output divided by row-sum. vT is XOR-swizzled (col ^ (row>>3)<<5) to kill
// the transpose-build bank conflicts.
// ---------------------------------------------------------------------------
__global__ __launch_bounds__(256) void k_attn(
    const bf16* __restrict__ qbh, const bf16* __restrict__ kbh,
    const bf16* __restrict__ vbh, const bf16* __restrict__ T5,
    bf16* __restrict__ aob)
{
  __shared__ bf16 qs[256 * 40];   // 20.0 KB, slot-permuted q-projection
  __shared__ bf16 vT[32 * 264];   // 16.5 KB, swizzled V^T
  const int tid = threadIdx.x;
  const int s = blockIdx.x >> 2, h = blockIdx.x & 3;
  const int rb = s * 256;
  const bf16* qh = qbh + (size_t)h * P * 32;
  const bf16* kh = kbh + (size_t)h * P * 32;
  const bf16* vh = vbh + (size_t)h * P * 32;
  const bf16* T5h = T5 + (size_t)h * 65536;

  // stage q (slot-permuted rows, stride 40) and vT (swizzled transpose)
  #pragma unroll
  for (int i = 0; i < 4; ++i) {
    const int flat = i*2048 + tid*8;
    const int pos = flat >> 5, cc = flat & 31;
    // sigma: pos bits [7:5]=kt [4:3]=c2 [2]=half [1:0]=m -> slot bits
    //        [7:5]=kt [4]=half [3:2]=c2 [1:0]=m   (bijective bit swap)
    const int slot = (pos & 0xE3) | ((pos & 0x04) << 2) | ((pos & 0x18) >> 1);
    bf16x8 qv = *(const bf16x8*)(qh + ((size_t)rb + pos)*32 + cc);
    *(bf16x8*)(qs + slot*40 + cc) = qv;
    bf16x8 vv = *(const bf16x8*)(vh + ((size_t)rb + pos)*32 + cc);
    #pragma unroll
    for (int j = 0; j < 8; ++j) {
      const int row = cc + j;
      vT[row*264 + (pos ^ ((row >> 3) << 5))] = vv[j];
    }
  }
  __syncthreads();

  const int w = tid >> 6, lane = tid & 63, g = lane >> 4, l15 = lane & 15;

  // hoist PV A-fragments from swizzled vT (once per block)
  bf16x8 av[2][8];
  #pragma unroll
  for (int mt = 0; mt < 2; ++mt) {
    const int row = 16*mt + l15;
    const int X = (row >> 3) << 5;
    #pragma unroll
    for (int kt = 0; kt < 8; ++kt)
      av[mt][kt] = *(const bf16x8*)(vT + row*264 + ((32*kt + 8*g) ^ X));
  }

  bf16* aoh = aob + (size_t)h * P * 32;
  const f32x4 z = {0.f, 0.f, 0.f, 0.f};

  for (int qt = 0; qt < 4; ++qt) {
    const int q = w*64 + qt*16 + l15;
    // B-frag: k-projection row q (carries the softmax's q index on cols)
    bf16x8 bq = *(const bf16x8*)(kh + ((size_t)rb + q)*32 + 8*g);
    const bf16* Trow = T5h + (size_t)q * 256 + 8*g;
    f32x4 o0 = z, o1 = z;
    float rs = 0.f;
    #pragma unroll
    for (int kt = 0; kt < 8; ++kt) {
      bf16x8 a0 = *(const bf16x8*)(qs + (16*(2*kt + 0) + l15)*40 + 8*g);
      bf16x8 a1 = *(const bf16x8*)(qs + (16*(2*kt + 1) + l15)*40 + 8*g);
      f32x4 s0 = MFMA(a0, bq, z);
      f32x4 s1 = MFMA(a1, bq, z);
      bf16x4 b0 = *(const bf16x4*)(Trow + 32*kt);
      bf16x4 b1 = *(const bf16x4*)(Trow + 32*kt + 4);
      bf16x8 pf;
      #pragma unroll
      for (int r = 0; r < 4; ++r) {
        float e0 = __expf(s0[r] + (float)b0[r]);
        float e1 = __expf(s1[r] + (float)b1[r]);
        pf[r]     = (bf16)e0;
        pf[4 + r] = (bf16)e1;
        rs += (float)pf[r] + (float)pf[4 + r];  // sum the rounded weights
      }
      o0 = MFMA(av[0][kt], pf, o0);
      o1 = MFMA(av[1][kt], pf, o1);
    }
    rs += __shfl_xor(rs, 16);
    rs += __shfl_xor(rs, 32);
    const float inv = 1.f / rs;
    bf16x4 p0, p1;
    #pragma unroll
    for (int r = 0; r < 4; ++r) {
      p0[r] = (bf16)(o0[r] * inv);
      p1[r] = (bf16)(o1[r] * inv);
    }
    bf16* dst = aoh + ((size_t)rb + q)*32;
    *(bf16x4*)(dst + 4*g)      = p0;
    *(bf16x4*)(dst + 16 + 4*g) = p1;
  }
}

// ---------------------------------------------------------------------------
// k_gate_out: out = (ao * gate) @ Wo + bo via MFMA; WoF fragment-ordered.
// NEW: the wave's 8 WoF A-fragments are hoisted into VGPRs pre-barrier
// (removes the 4x per-nt reload, latency hides under the barrier wait).
// ---------------------------------------------------------------------------
__global__ __launch_bounds__(256) void k_gate_out(
    const bf16* __restrict__ aob, const bf16* __restrict__ gfb,
    const bf16* __restrict__ WoF, const float* __restrict__ bo,
    float* __restrict__ out)
{
  __shared__ bf16 gs[64 * 136];
  const int tid = threadIdx.x;
  const int base = blockIdx.x * 64;
  const int w = tid >> 6, lane = tid & 63, g = lane >> 4, l15 = lane & 15;

  #pragma unroll
  for (int i = 0; i < 4; ++i) {
    const int flat = i*2048 + tid*8;
    const int pos = flat >> 7, c = flat & 127, h = c >> 5;
    bf16x8 a = *(const bf16x8*)(aob + ((size_t)h*P + base + pos)*32 + (c & 31));
    bf16x8 f = *(const bf16x8*)(gfb + ((size_t)(base + pos))*128 + c);
    bf16x8 o;
    #pragma unroll
    for (int j = 0; j < 8; ++j) o[j] = (bf16)((float)a[j] * (float)f[j]);
    *(bf16x8*)(gs + pos*136 + c) = o;
  }

  // hoist the wave's 8 WoF A-fragments (mt2 in {0,1} x kt in 0..3)
  bf16x8 wf[8];
  #pragma unroll
  for (int j = 0; j < 8; ++j)
    wf[j] = *(const bf16x8*)(WoF + ((size_t)((2*w + (j >> 2))*4 + (j & 3))*64 + lane)*8);

  __syncthreads();

  const f32x4 z = {0.f, 0.f, 0.f, 0.f};

  for (int nt = 0; nt < 4; ++nt) {
    bf16x8 bfr[4];
    #pragma unroll
    for (int kt = 0; kt < 4; ++kt)
      bfr[kt] = *(const bf16x8*)(gs + (16*nt + l15)*136 + 32*kt + 8*g);
    f32x4 a0 = z, a1 = z;
    #pragma unroll
    for (int kt = 0; kt < 4; ++kt) {
      a0 = MFMA(wf[kt],     bfr[kt], a0);
      a1 = MFMA(wf[4 + kt], bfr[kt], a1);
    }
    const int pos = base + 16*nt + l15;
    {
      const int col = 16*(2*w + 0) + 4*g;
      float4 bb = *(const float4*)(bo + col);
      *(float4*)(out + (size_t)pos*128 + col) =
          make_float4(a0[0] + bb.x, a0[1] + bb.y, a0[2] + bb.z, a0[3] + bb.w);
    }
    {
      const int col = 16*(2*w + 1) + 4*g;
      float4 bb = *(const float4*)(bo + col);
      *(float4*)(out + (size_t)pos*128 + col) =
          make_float4(a1[0] + bb.x, a1[1] + bb.y, a1[2] + bb.z, a1[3] + bb.w);
    }
  }
}

// ---------------------------------------------------------------------------
extern "C" void kernel_launch(void* const* d_in, const int* in_sizes, int n_in,
                              void* d_out, int out_size, void* d_ws, size_t ws_size,
                              hipStream_t stream) {
  const float* pr    = (const float*)d_in[0];
  const float* mask  = (const float*)d_in[1];
  const float* gamma = (const float*)d_in[2];
  const float* beta  = (const float*)d_in[3];
  const float* Wq    = (const float*)d_in[4];
  const float* Wk    = (const float*)d_in[5];
  const float* Wv    = (const float*)d_in[6];
  const float* Wb    = (const float*)d_in[7];
  const float* Wfu   = (const float*)d_in[8];
  const float* bfu   = (const float*)d_in[9];
  const float* Wo    = (const float*)d_in[10];
  const float* bo    = (const float*)d_in[11];
  float* out = (float*)d_out;

  bf16* qbh = (bf16*)d_ws;                        // H*P*32
  bf16* kbh = qbh + (size_t)H * P * 32;
  bf16* vbh = kbh + (size_t)H * P * 32;
  bf16* gfb = vbh + (size_t)H * P * 32;           // P*128
  bf16* aob = gfb + (size_t)P * 128;              // H*P*32
  bf16* T5  = aob + (size_t)H * P * 32;           // H*65536 = H*P
  bf16* WF  = T5  + (size_t)H * P;                // 4*16384
  bf16* WoF = WF  + 4 * 16384;                    // 16384
  bf16* WbF = WoF + 16384;                        // 2048
  float* pb = (float*)(WbF + 2048);               // P*4 fp32

  k_prep<<<41, 256, 0, stream>>>(Wq, Wk, Wv, Wfu, Wo, Wb, WF, WoF, WbF);
  k_ln_proj<<<1024, 256, 0, stream>>>(pr, gamma, beta, bfu, WF, WbF,
                                      qbh, kbh, vbh, gfb, pb);
  k_bias<<<256, 256, 0, stream>>>(mask, pb, T5);
  k_attn<<<1024, 256, 0, stream>>>(qbh, kbh, vbh, T5, aob);
  k_gate_out<<<1024, 256, 0, stream>>>(aob, gfb, WoF, bo, out);
}

// Round 3
// 183.103 us; speedup vs baseline: 1.1094x; 1.0038x over previous
//
#include <hip/hip_runtime.h>
#include <math.h>

#define L 256
#define E 128
#define H 4
#define C 32
#define P (L*L)  // 65536

typedef __bf16 bf16;
typedef __bf16 bf16x8 __attribute__((ext_vector_type(8)));
typedef __bf16 bf16x4 __attribute__((ext_vector_type(4)));
typedef float  f32x4  __attribute__((ext_vector_type(4)));

#define MFMA(a,b,c) __builtin_amdgcn_mfma_f32_16x16x32_bf16((a),(b),(c),0,0,0)

// ---------------------------------------------------------------------------
// k_prep: emit weights in MFMA A-fragment order. Grid 41: blocks 0..39 cover
// (m, frag-quad) with one fragment per wave; block 40 builds WbF.
// frag f=mt*4+kt; elem j at lane (g,l15) is A[row=16mt+l15][k=32kt+8g+j]
// = W[k][row] (*C^-0.5 for Wq). WbF: rows 0..3 = Wb columns, rows 4..15 zero.
// ---------------------------------------------------------------------------
__global__ __launch_bounds__(256) void k_prep(
    const float* __restrict__ Wq, const float* __restrict__ Wk,
    const float* __restrict__ Wv, const float* __restrict__ Wfu,
    const float* __restrict__ Wo, const float* __restrict__ Wb,
    bf16* __restrict__ WF, bf16* __restrict__ WoF, bf16* __restrict__ WbF)
{
  const int b = blockIdx.x;  // 0..40
  const int lane = threadIdx.x & 63, wv = threadIdx.x >> 6;
  const int g = lane >> 4, l15 = lane & 15;
  if (b < 40) {
    const int m = b >> 3;
    const int f = (b & 7) * 4 + wv;
    const float* W = (m==0)?Wq:(m==1)?Wk:(m==2)?Wv:(m==3)?Wfu:Wo;
    bf16* dst = (m < 4) ? (WF + (size_t)m * 16384) : WoF;
    const float sc = (m == 0) ? 0.17677669529663689f : 1.0f;
    const int mt = f >> 2, kt = f & 3;
    const int row = 16*mt + l15, k0 = 32*kt + 8*g;
    bf16x8 o;
    #pragma unroll
    for (int j = 0; j < 8; ++j) o[j] = (bf16)(W[(size_t)(k0+j)*128 + row] * sc);
    *(bf16x8*)(dst + ((size_t)f*64 + lane)*8) = o;
  } else {
    const int kt = wv, k0 = 32*kt + 8*g;
    bf16x8 o;
    #pragma unroll
    for (int j = 0; j < 8; ++j)
      o[j] = (l15 < 4) ? (bf16)Wb[(size_t)(k0+j)*4 + l15] : (bf16)0.0f;
    *(bf16x8*)(WbF + ((size_t)kt*64 + lane)*8) = o;
  }
}

// ---------------------------------------------------------------------------
// k_ln_proj: LN -> bf16 x in LDS; per-wave matrix (q,k,v,gate) via MFMA.
// Weight A-fragments are loaded ONCE per block into 128 VGPRs, pinned there
// with an opaque asm touch (the round-1 attempt was silently sunk back into
// the loop: VGPR stayed 112). __launch_bounds__(256,2) raises the register
// budget so 128 weight regs + LN working set fit without spill (2 blocks/CU).
// q,k,v head-major [h][P][32]; gate [P][128]; pb [P][4] fp32.
// ---------------------------------------------------------------------------
__global__ __launch_bounds__(256, 2) void k_ln_proj(
    const float* __restrict__ pr, const float* __restrict__ gamma,
    const float* __restrict__ beta, const float* __restrict__ bfu,
    const bf16* __restrict__ WF, const bf16* __restrict__ WbF,
    bf16* __restrict__ qbh, bf16* __restrict__ kbh, bf16* __restrict__ vbh,
    bf16* __restrict__ gfb, float* __restrict__ pbo)
{
  __shared__ bf16 xs[64 * 136];        // 17.0 KB
  __shared__ bf16 stag[4][16 * 136];   // 17.0 KB
  const int tid = threadIdx.x;
  const int base = blockIdx.x * 64;
  const int w = tid >> 6, lane = tid & 63, g = lane >> 4, l15 = lane & 15;

  // --- issue this wave's 32 weight A-fragment loads FIRST (f32x4 views);
  //     they fly concurrently with the LN's pr reads ---
  const bf16* WFw = WF + (size_t)w * 16384;
  f32x4 af[32];
  #pragma unroll
  for (int f = 0; f < 32; ++f)
    af[f] = *(const f32x4*)(WFw + ((size_t)f*64 + lane)*8);

  // --- LayerNorm (4 threads per position) ---
  {
    const int pl = tid >> 2, sub = tid & 3;
    const float4* src = (const float4*)(pr + (size_t)(base + pl) * 128 + sub * 32);
    float4 r[8];
    float s = 0.f, ss = 0.f;
    #pragma unroll
    for (int j = 0; j < 8; ++j) {
      r[j] = src[j];
      s  += r[j].x + r[j].y + r[j].z + r[j].w;
      ss += r[j].x*r[j].x + r[j].y*r[j].y + r[j].z*r[j].z + r[j].w*r[j].w;
    }
    s  += __shfl_xor(s, 1, 4);  s  += __shfl_xor(s, 2, 4);
    ss += __shfl_xor(ss, 1, 4); ss += __shfl_xor(ss, 2, 4);
    const float mu   = s * 0.0078125f;
    const float var  = ss * 0.0078125f - mu * mu;
    const float rstd = rsqrtf(var + 1e-5f);
    const float4* g4 = (const float4*)(gamma + sub * 32);
    const float4* b4 = (const float4*)(beta + sub * 32);
    bf16* xr = xs + pl * 136 + sub * 32;
    #pragma unroll
    for (int i = 0; i < 4; ++i) {
      float4 r0 = r[2*i], r1 = r[2*i+1];
      float4 gg0 = g4[2*i], gg1 = g4[2*i+1], bb0 = b4[2*i], bb1 = b4[2*i+1];
      bf16x8 o;
      o[0] = (bf16)((r0.x - mu) * rstd * gg0.x + bb0.x);
      o[1] = (bf16)((r0.y - mu) * rstd * gg0.y + bb0.y);
      o[2] = (bf16)((r0.z - mu) * rstd * gg0.z + bb0.z);
      o[3] = (bf16)((r0.w - mu) * rstd * gg0.w + bb0.w);
      o[4] = (bf16)((r1.x - mu) * rstd * gg1.x + bb1.x);
      o[5] = (bf16)((r1.y - mu) * rstd * gg1.y + bb1.y);
      o[6] = (bf16)((r1.z - mu) * rstd * gg1.z + bb1.z);
      o[7] = (bf16)((r1.w - mu) * rstd * gg1.w + bb1.w);
      *(bf16x8*)(xr + 8 * i) = o;
    }
  }

  // --- pin the weight fragments in VGPRs: opaque to the scheduler, so the
  //     loads cannot be sunk into the nt loop; all later uses read these regs
  #pragma unroll
  for (int f = 0; f < 32; ++f)
    asm volatile("" : "+v"(af[f]));

  __syncthreads();

  const f32x4 z = {0.f, 0.f, 0.f, 0.f};

  // --- pair_bias via MFMA: wave w covers positions base+16w..base+16w+15 ---
  {
    f32x4 acc = z;
    #pragma unroll
    for (int kt = 0; kt < 4; ++kt) {
      bf16x8 a = *(const bf16x8*)(WbF + ((size_t)kt*64 + lane)*8);
      bf16x8 b = *(const bf16x8*)(xs + (16*w + l15)*136 + 32*kt + 8*g);
      acc = MFMA(a, b, acc);
    }
    if (g == 0)
      *(float4*)(pbo + (size_t)(base + 16*w + l15)*4) =
          make_float4(acc[0], acc[1], acc[2], acc[3]);
  }

  // --- projection: wave w -> matrix w (pure LDS-read + MFMA now) ---
  bf16* stw = stag[w];

  for (int nt = 0; nt < 4; ++nt) {
    bf16x8 bfr[4];
    #pragma unroll
    for (int kt = 0; kt < 4; ++kt)
      bfr[kt] = *(const bf16x8*)(xs + (16*nt + l15)*136 + 32*kt + 8*g);
    f32x4 acc[8];
    #pragma unroll
    for (int mt = 0; mt < 8; ++mt) acc[mt] = z;
    #pragma unroll
    for (int kt = 0; kt < 4; ++kt)
      #pragma unroll
      for (int mt = 0; mt < 8; ++mt)
        acc[mt] = MFMA(__builtin_bit_cast(bf16x8, af[mt*4 + kt]), bfr[kt], acc[mt]);

    // epilogue -> LDS staging (D: col=16mt+4g+r, pos=l15)
    #pragma unroll
    for (int mt = 0; mt < 8; ++mt) {
      const int col = 16*mt + 4*g;
      f32x4 vv = acc[mt];
      if (w == 3) {
        float4 bb = *(const float4*)(bfu + col);
        vv[0] = 1.f / (1.f + __expf(-(vv[0] + bb.x)));
        vv[1] = 1.f / (1.f + __expf(-(vv[1] + bb.y)));
        vv[2] = 1.f / (1.f + __expf(-(vv[2] + bb.z)));
        vv[3] = 1.f / (1.f + __expf(-(vv[3] + bb.w)));
      }
      bf16x4 o;
      o[0] = (bf16)vv[0]; o[1] = (bf16)vv[1]; o[2] = (bf16)vv[2]; o[3] = (bf16)vv[3];
      *(bf16x4*)(stw + l15*136 + col) = o;
    }

    // coalesced global store (same-wave LDS ordering guarantees visibility)
    #pragma unroll
    for (int i = 0; i < 4; ++i) {
      const int flat = i*512 + lane*8;
      const int p = flat >> 7, c = flat & 127;
      bf16x8 val = *(const bf16x8*)(stw + p*136 + c);
      if (w == 3) {
        *(bf16x8*)(gfb + ((size_t)(base + 16*nt + p))*128 + c) = val;
      } else {
        bf16* dst = (w == 0) ? qbh : (w == 1) ? kbh : vbh;
        const int h = c >> 5;
        *(bf16x8*)(dst + ((size_t)h*P + base + 16*nt + p)*32 + (c & 31)) = val;
      }
    }
  }
}

// ---------------------------------------------------------------------------
// k_bias: T5[h][q][v] = mask[q,v] + pb[q,v,h]  (bf16). grid 256 (q), 256 thr.
// ---------------------------------------------------------------------------
__global__ __launch_bounds__(256) void k_bias(
    const float* __restrict__ mask, const float* __restrict__ pb,
    bf16* __restrict__ T5)
{
  const int q = blockIdx.x;
  const int v = threadIdx.x;
  const size_t qv = (size_t)q*256 + v;
  const float m = mask[qv];
  float4 p = *(const float4*)(pb + qv*4);
  T5[qv]            = (bf16)(m + p.x);
  T5[qv +   65536]  = (bf16)(m + p.y);
  T5[qv + 2*65536]  = (bf16)(m + p.z);
  T5[qv + 3*65536]  = (bf16)(m + p.w);
}

// ---------------------------------------------------------------------------
// k_attn: block=(s,h), 4 waves x 64 q-rows. Swapped QK^T orientation; P stays
// lane-local (no LDS round-trip); softmax via 2 shfl_xor; vT XOR-swizzled.
// ---------------------------------------------------------------------------
__global__ __launch_bounds__(256) void k_attn(
    const bf16* __restrict__ qbh, const bf16* __restrict__ kbh,
    const bf16* __restrict__ vbh, const bf16* __restrict__ T5,
    bf16* __restrict__ aob)
{
  __shared__ bf16 qs[256 * 40];   // 20.0 KB, slot-permuted q-projection
  __shared__ bf16 vT[32 * 264];   // 16.5 KB, swizzled V^T
  const int tid = threadIdx.x;
  const int s = blockIdx.x >> 2, h = blockIdx.x & 3;
  const int rb = s * 256;
  const bf16* qh = qbh + (size_t)h * P * 32;
  const bf16* kh = kbh + (size_t)h * P * 32;
  const bf16* vh = vbh + (size_t)h * P * 32;
  const bf16* T5h = T5 + (size_t)h * 65536;

  // stage q (slot-permuted rows, stride 40) and vT (swizzled transpose)
  #pragma unroll
  for (int i = 0; i < 4; ++i) {
    const int flat = i*2048 + tid*8;
    const int pos = flat >> 5, cc = flat & 31;
    const int slot = (pos & 0xE3) | ((pos & 0x04) << 2) | ((pos & 0x18) >> 1);
    bf16x8 qv = *(const bf16x8*)(qh + ((size_t)rb + pos)*32 + cc);
    *(bf16x8*)(qs + slot*40 + cc) = qv;
    bf16x8 vv = *(const bf16x8*)(vh + ((size_t)rb + pos)*32 + cc);
    #pragma unroll
    for (int j = 0; j < 8; ++j) {
      const int row = cc + j;
      vT[row*264 + (pos ^ ((row >> 3) << 5))] = vv[j];
    }
  }
  __syncthreads();

  const int w = tid >> 6, lane = tid & 63, g = lane >> 4, l15 = lane & 15;

  // hoist PV A-fragments from swizzled vT (once per block)
  bf16x8 av[2][8];
  #pragma unroll
  for (int mt = 0; mt < 2; ++mt) {
    const int row = 16*mt + l15;
    const int X = (row >> 3) << 5;
    #pragma unroll
    for (int kt = 0; kt < 8; ++kt)
      av[mt][kt] = *(const bf16x8*)(vT + row*264 + ((32*kt + 8*g) ^ X));
  }

  bf16* aoh = aob + (size_t)h * P * 32;
  const f32x4 z = {0.f, 0.f, 0.f, 0.f};

  for (int qt = 0; qt < 4; ++qt) {
    const int q = w*64 + qt*16 + l15;
    bf16x8 bq = *(const bf16x8*)(kh + ((size_t)rb + q)*32 + 8*g);
    const bf16* Trow = T5h + (size_t)q * 256 + 8*g;
    f32x4 o0 = z, o1 = z;
    float rs = 0.f;
    #pragma unroll
    for (int kt = 0; kt < 8; ++kt) {
      bf16x8 a0 = *(const bf16x8*)(qs + (16*(2*kt + 0) + l15)*40 + 8*g);
      bf16x8 a1 = *(const bf16x8*)(qs + (16*(2*kt + 1) + l15)*40 + 8*g);
      f32x4 s0 = MFMA(a0, bq, z);
      f32x4 s1 = MFMA(a1, bq, z);
      bf16x4 b0 = *(const bf16x4*)(Trow + 32*kt);
      bf16x4 b1 = *(const bf16x4*)(Trow + 32*kt + 4);
      bf16x8 pf;
      #pragma unroll
      for (int r = 0; r < 4; ++r) {
        float e0 = __expf(s0[r] + (float)b0[r]);
        float e1 = __expf(s1[r] + (float)b1[r]);
        pf[r]     = (bf16)e0;
        pf[4 + r] = (bf16)e1;
        rs += (float)pf[r] + (float)pf[4 + r];  // sum the rounded weights
      }
      o0 = MFMA(av[0][kt], pf, o0);
      o1 = MFMA(av[1][kt], pf, o1);
    }
    rs += __shfl_xor(rs, 16);
    rs += __shfl_xor(rs, 32);
    const float inv = 1.f / rs;
    bf16x4 p0, p1;
    #pragma unroll
    for (int r = 0; r < 4; ++r) {
      p0[r] = (bf16)(o0[r] * inv);
      p1[r] = (bf16)(o1[r] * inv);
    }
    bf16* dst = aoh + ((size_t)rb + q)*32;
    *(bf16x4*)(dst + 4*g)      = p0;
    *(bf16x4*)(dst + 16 + 4*g) = p1;
  }
}

// ---------------------------------------------------------------------------
// k_gate_out: out = (ao * gate) @ Wo + bo via MFMA; WoF fragment-ordered.
// WoF fragments hoisted + asm-pinned (same discipline as k_ln_proj).
// ---------------------------------------------------------------------------
__global__ __launch_bounds__(256) void k_gate_out(
    const bf16* __restrict__ aob, const bf16* __restrict__ gfb,
    const bf16* __restrict__ WoF, const float* __restrict__ bo,
    float* __restrict__ out)
{
  __shared__ bf16 gs[64 * 136];
  const int tid = threadIdx.x;
  const int base = blockIdx.x * 64;
  const int w = tid >> 6, lane = tid & 63, g = lane >> 4, l15 = lane & 15;

  // hoist the wave's 8 WoF A-fragments (mt2 in {0,1} x kt in 0..3)
  f32x4 wf[8];
  #pragma unroll
  for (int j = 0; j < 8; ++j)
    wf[j] = *(const f32x4*)(WoF + ((size_t)((2*w + (j >> 2))*4 + (j & 3))*64 + lane)*8);

  #pragma unroll
  for (int i = 0; i < 4; ++i) {
    const int flat = i*2048 + tid*8;
    const int pos = flat >> 7, c = flat & 127, h = c >> 5;
    bf16x8 a = *(const bf16x8*)(aob + ((size_t)h*P + base + pos)*32 + (c & 31));
    bf16x8 f = *(const bf16x8*)(gfb + ((size_t)(base + pos))*128 + c);
    bf16x8 o;
    #pragma unroll
    for (int j = 0; j < 8; ++j) o[j] = (bf16)((float)a[j] * (float)f[j]);
    *(bf16x8*)(gs + pos*136 + c) = o;
  }

  #pragma unroll
  for (int j = 0; j < 8; ++j)
    asm volatile("" : "+v"(wf[j]));

  __syncthreads();

  const f32x4 z = {0.f, 0.f, 0.f, 0.f};

  for (int nt = 0; nt < 4; ++nt) {
    bf16x8 bfr[4];
    #pragma unroll
    for (int kt = 0; kt < 4; ++kt)
      bfr[kt] = *(const bf16x8*)(gs + (16*nt + l15)*136 + 32*kt + 8*g);
    f32x4 a0 = z, a1 = z;
    #pragma unroll
    for (int kt = 0; kt < 4; ++kt) {
      a0 = MFMA(__builtin_bit_cast(bf16x8, wf[kt]),     bfr[kt], a0);
      a1 = MFMA(__builtin_bit_cast(bf16x8, wf[4 + kt]), bfr[kt], a1);
    }
    const int pos = base + 16*nt + l15;
    {
      const int col = 16*(2*w + 0) + 4*g;
      float4 bb = *(const float4*)(bo + col);
      *(float4*)(out + (size_t)pos*128 + col) =
          make_float4(a0[0] + bb.x, a0[1] + bb.y, a0[2] + bb.z, a0[3] + bb.w);
    }
    {
      const int col = 16*(2*w + 1) + 4*g;
      float4 bb = *(const float4*)(bo + col);
      *(float4*)(out + (size_t)pos*128 + col) =
          make_float4(a1[0] + bb.x, a1[1] + bb.y, a1[2] + bb.z, a1[3] + bb.w);
    }
  }
}

// ---------------------------------------------------------------------------
extern "C" void kernel_launch(void* const* d_in, const int* in_sizes, int n_in,
                              void* d_out, int out_size, void* d_ws, size_t ws_size,
                              hipStream_t stream) {
  const float* pr    = (const float*)d_in[0];
  const float* mask  = (const float*)d_in[1];
  const float* gamma = (const float*)d_in[2];
  const float* beta  = (const float*)d_in[3];
  const float* Wq    = (const float*)d_in[4];
  const float* Wk    = (const float*)d_in[5];
  const float* Wv    = (const float*)d_in[6];
  const float* Wb    = (const float*)d_in[7];
  const float* Wfu   = (const float*)d_in[8];
  const float* bfu   = (const float*)d_in[9];
  const float* Wo    = (const float*)d_in[10];
  const float* bo    = (const float*)d_in[11];
  float* out = (float*)d_out;

  bf16* qbh = (bf16*)d_ws;                        // H*P*32
  bf16* kbh = qbh + (size_t)H * P * 32;
  bf16* vbh = kbh + (size_t)H * P * 32;
  bf16* gfb = vbh + (size_t)H * P * 32;           // P*128
  bf16* aob = gfb + (size_t)P * 128;              // H*P*32
  bf16* T5  = aob + (size_t)H * P * 32;           // H*65536 = H*P
  bf16* WF  = T5  + (size_t)H * P;                // 4*16384
  bf16* WoF = WF  + 4 * 16384;                    // 16384
  bf16* WbF = WoF + 16384;                        // 2048
  float* pb = (float*)(WbF + 2048);               // P*4 fp32

  k_prep<<<41, 256, 0, stream>>>(Wq, Wk, Wv, Wfu, Wo, Wb, WF, WoF, WbF);
  k_ln_proj<<<1024, 256, 0, stream>>>(pr, gamma, beta, bfu, WF, WbF,
                                      qbh, kbh, vbh, gfb, pb);
  k_bias<<<256, 256, 0, stream>>>(mask, pb, T5);
  k_attn<<<1024, 256, 0, stream>>>(qbh, kbh, vbh, T5, aob);
  k_gate_out<<<1024, 256, 0, stream>>>(aob, gfb, WoF, bo, out);
}

// Round 4
// 172.606 us; speedup vs baseline: 1.1769x; 1.0608x over previous
//
#include <hip/hip_runtime.h>
#include <math.h>

#define L 256
#define E 128
#define H 4
#define C 32
#define P (L*L)  // 65536

typedef __bf16 bf16;
typedef __bf16 bf16x8 __attribute__((ext_vector_type(8)));
typedef __bf16 bf16x4 __attribute__((ext_vector_type(4)));
typedef float  f32x4  __attribute__((ext_vector_type(4)));

#define MFMA(a,b,c) __builtin_amdgcn_mfma_f32_16x16x32_bf16((a),(b),(c),0,0,0)

// ---------------------------------------------------------------------------
// k_prep: emit weights in MFMA A-fragment order. Grid 41: blocks 0..39 cover
// (m, frag-quad) with one fragment per wave; block 40 builds WbF.
// frag f=mt*4+kt; elem j at lane (g,l15) is A[row=16mt+l15][k=32kt+8g+j]
// = W[k][row] (*C^-0.5 for Wq). WbF: rows 0..3 = Wb columns, rows 4..15 zero.
// ---------------------------------------------------------------------------
__global__ __launch_bounds__(256) void k_prep(
    const float* __restrict__ Wq, const float* __restrict__ Wk,
    const float* __restrict__ Wv, const float* __restrict__ Wfu,
    const float* __restrict__ Wo, const float* __restrict__ Wb,
    bf16* __restrict__ WF, bf16* __restrict__ WoF, bf16* __restrict__ WbF)
{
  const int b = blockIdx.x;  // 0..40
  const int lane = threadIdx.x & 63, wv = threadIdx.x >> 6;
  const int g = lane >> 4, l15 = lane & 15;
  if (b < 40) {
    const int m = b >> 3;
    const int f = (b & 7) * 4 + wv;
    const float* W = (m==0)?Wq:(m==1)?Wk:(m==2)?Wv:(m==3)?Wfu:Wo;
    bf16* dst = (m < 4) ? (WF + (size_t)m * 16384) : WoF;
    const float sc = (m == 0) ? 0.17677669529663689f : 1.0f;
    const int mt = f >> 2, kt = f & 3;
    const int row = 16*mt + l15, k0 = 32*kt + 8*g;
    bf16x8 o;
    #pragma unroll
    for (int j = 0; j < 8; ++j) o[j] = (bf16)(W[(size_t)(k0+j)*128 + row] * sc);
    *(bf16x8*)(dst + ((size_t)f*64 + lane)*8) = o;
  } else {
    const int kt = wv, k0 = 32*kt + 8*g;
    bf16x8 o;
    #pragma unroll
    for (int j = 0; j < 8; ++j)
      o[j] = (l15 < 4) ? (bf16)Wb[(size_t)(k0+j)*4 + l15] : (bf16)0.0f;
    *(bf16x8*)(WbF + ((size_t)kt*64 + lane)*8) = o;
  }
}

// ---------------------------------------------------------------------------
// k_ln_proj: LN -> bf16 x in LDS; per-wave matrix (q,k,v,gate) via MFMA.
// Weight A-fragments loaded once per block into VGPRs, asm-pinned.
// q,k,v head-major [h][P][32]; gate [P][128]; pb [P][4] fp32.
// ---------------------------------------------------------------------------
__global__ __launch_bounds__(256, 2) void k_ln_proj(
    const float* __restrict__ pr, const float* __restrict__ gamma,
    const float* __restrict__ beta, const float* __restrict__ bfu,
    const bf16* __restrict__ WF, const bf16* __restrict__ WbF,
    bf16* __restrict__ qbh, bf16* __restrict__ kbh, bf16* __restrict__ vbh,
    bf16* __restrict__ gfb, float* __restrict__ pbo)
{
  __shared__ bf16 xs[64 * 136];        // 17.0 KB
  __shared__ bf16 stag[4][16 * 136];   // 17.0 KB
  const int tid = threadIdx.x;
  const int base = blockIdx.x * 64;
  const int w = tid >> 6, lane = tid & 63, g = lane >> 4, l15 = lane & 15;

  // --- issue this wave's 32 weight A-fragment loads FIRST (f32x4 views);
  //     they fly concurrently with the LN's pr reads ---
  const bf16* WFw = WF + (size_t)w * 16384;
  f32x4 af[32];
  #pragma unroll
  for (int f = 0; f < 32; ++f)
    af[f] = *(const f32x4*)(WFw + ((size_t)f*64 + lane)*8);

  // --- LayerNorm (4 threads per position) ---
  {
    const int pl = tid >> 2, sub = tid & 3;
    const float4* src = (const float4*)(pr + (size_t)(base + pl) * 128 + sub * 32);
    float4 r[8];
    float s = 0.f, ss = 0.f;
    #pragma unroll
    for (int j = 0; j < 8; ++j) {
      r[j] = src[j];
      s  += r[j].x + r[j].y + r[j].z + r[j].w;
      ss += r[j].x*r[j].x + r[j].y*r[j].y + r[j].z*r[j].z + r[j].w*r[j].w;
    }
    s  += __shfl_xor(s, 1, 4);  s  += __shfl_xor(s, 2, 4);
    ss += __shfl_xor(ss, 1, 4); ss += __shfl_xor(ss, 2, 4);
    const float mu   = s * 0.0078125f;
    const float var  = ss * 0.0078125f - mu * mu;
    const float rstd = rsqrtf(var + 1e-5f);
    const float4* g4 = (const float4*)(gamma + sub * 32);
    const float4* b4 = (const float4*)(beta + sub * 32);
    bf16* xr = xs + pl * 136 + sub * 32;
    #pragma unroll
    for (int i = 0; i < 4; ++i) {
      float4 r0 = r[2*i], r1 = r[2*i+1];
      float4 gg0 = g4[2*i], gg1 = g4[2*i+1], bb0 = b4[2*i], bb1 = b4[2*i+1];
      bf16x8 o;
      o[0] = (bf16)((r0.x - mu) * rstd * gg0.x + bb0.x);
      o[1] = (bf16)((r0.y - mu) * rstd * gg0.y + bb0.y);
      o[2] = (bf16)((r0.z - mu) * rstd * gg0.z + bb0.z);
      o[3] = (bf16)((r0.w - mu) * rstd * gg0.w + bb0.w);
      o[4] = (bf16)((r1.x - mu) * rstd * gg1.x + bb1.x);
      o[5] = (bf16)((r1.y - mu) * rstd * gg1.y + bb1.y);
      o[6] = (bf16)((r1.z - mu) * rstd * gg1.z + bb1.z);
      o[7] = (bf16)((r1.w - mu) * rstd * gg1.w + bb1.w);
      *(bf16x8*)(xr + 8 * i) = o;
    }
  }

  // --- pin the weight fragments in VGPRs ---
  #pragma unroll
  for (int f = 0; f < 32; ++f)
    asm volatile("" : "+v"(af[f]));

  __syncthreads();

  const f32x4 z = {0.f, 0.f, 0.f, 0.f};

  // --- pair_bias via MFMA: wave w covers positions base+16w..base+16w+15 ---
  {
    f32x4 acc = z;
    #pragma unroll
    for (int kt = 0; kt < 4; ++kt) {
      bf16x8 a = *(const bf16x8*)(WbF + ((size_t)kt*64 + lane)*8);
      bf16x8 b = *(const bf16x8*)(xs + (16*w + l15)*136 + 32*kt + 8*g);
      acc = MFMA(a, b, acc);
    }
    if (g == 0)
      *(float4*)(pbo + (size_t)(base + 16*w + l15)*4) =
          make_float4(acc[0], acc[1], acc[2], acc[3]);
  }

  // --- projection: wave w -> matrix w (pure LDS-read + MFMA now) ---
  bf16* stw = stag[w];

  for (int nt = 0; nt < 4; ++nt) {
    bf16x8 bfr[4];
    #pragma unroll
    for (int kt = 0; kt < 4; ++kt)
      bfr[kt] = *(const bf16x8*)(xs + (16*nt + l15)*136 + 32*kt + 8*g);
    f32x4 acc[8];
    #pragma unroll
    for (int mt = 0; mt < 8; ++mt) acc[mt] = z;
    #pragma unroll
    for (int kt = 0; kt < 4; ++kt)
      #pragma unroll
      for (int mt = 0; mt < 8; ++mt)
        acc[mt] = MFMA(__builtin_bit_cast(bf16x8, af[mt*4 + kt]), bfr[kt], acc[mt]);

    // epilogue -> LDS staging (D: col=16mt+4g+r, pos=l15)
    #pragma unroll
    for (int mt = 0; mt < 8; ++mt) {
      const int col = 16*mt + 4*g;
      f32x4 vv = acc[mt];
      if (w == 3) {
        float4 bb = *(const float4*)(bfu + col);
        vv[0] = 1.f / (1.f + __expf(-(vv[0] + bb.x)));
        vv[1] = 1.f / (1.f + __expf(-(vv[1] + bb.y)));
        vv[2] = 1.f / (1.f + __expf(-(vv[2] + bb.z)));
        vv[3] = 1.f / (1.f + __expf(-(vv[3] + bb.w)));
      }
      bf16x4 o;
      o[0] = (bf16)vv[0]; o[1] = (bf16)vv[1]; o[2] = (bf16)vv[2]; o[3] = (bf16)vv[3];
      *(bf16x4*)(stw + l15*136 + col) = o;
    }

    // coalesced global store (same-wave LDS ordering guarantees visibility)
    #pragma unroll
    for (int i = 0; i < 4; ++i) {
      const int flat = i*512 + lane*8;
      const int p = flat >> 7, c = flat & 127;
      bf16x8 val = *(const bf16x8*)(stw + p*136 + c);
      if (w == 3) {
        *(bf16x8*)(gfb + ((size_t)(base + 16*nt + p))*128 + c) = val;
      } else {
        bf16* dst = (w == 0) ? qbh : (w == 1) ? kbh : vbh;
        const int h = c >> 5;
        *(bf16x8*)(dst + ((size_t)h*P + base + 16*nt + p)*32 + (c & 31)) = val;
      }
    }
  }
}

// ---------------------------------------------------------------------------
// k_bias: T5[h][q][v] = mask[q,v] + pb[q,v,h]  (bf16). grid 256 (q), 256 thr.
// ---------------------------------------------------------------------------
__global__ __launch_bounds__(256) void k_bias(
    const float* __restrict__ mask, const float* __restrict__ pb,
    bf16* __restrict__ T5)
{
  const int q = blockIdx.x;
  const int v = threadIdx.x;
  const size_t qv = (size_t)q*256 + v;
  const float m = mask[qv];
  float4 p = *(const float4*)(pb + qv*4);
  T5[qv]            = (bf16)(m + p.x);
  T5[qv +   65536]  = (bf16)(m + p.y);
  T5[qv + 2*65536]  = (bf16)(m + p.z);
  T5[qv + 3*65536]  = (bf16)(m + p.w);
}

// ---------------------------------------------------------------------------
// k_attn: block=(s,h), NOW 512 threads = 8 waves x 32 q-rows (2 q-tiles per
// wave): halves each wave's serial critical path and doubles resident waves
// for latency hiding. Swapped QK^T orientation; P stays lane-local; softmax
// row-sum uses the unrounded exps (drops 256 bf16->f32 re-converts per wave
// and is closer to the f32 reference). vT swizzle upgraded so the 4 tid&3
// sub-groups land on distinct bank offsets {0,16,8,24} (old one collapsed to
// {0,16} -> 4-way conflicts on the transpose writes). k-row B-fragments for
// both q-tiles prefetched before the barrier. o-accumulators split 2-way to
// shorten the 8-deep MFMA accumulate chain.
// ---------------------------------------------------------------------------
__global__ __launch_bounds__(512) void k_attn(
    const bf16* __restrict__ qbh, const bf16* __restrict__ kbh,
    const bf16* __restrict__ vbh, const bf16* __restrict__ T5,
    bf16* __restrict__ aob)
{
  __shared__ bf16 qs[256 * 40];   // 20.0 KB, slot-permuted q-projection
  __shared__ bf16 vT[32 * 264];   // 16.5 KB, swizzled V^T
  const int tid = threadIdx.x;    // 0..511
  const int s = blockIdx.x >> 2, h = blockIdx.x & 3;
  const int rb = s * 256;
  const bf16* qh = qbh + (size_t)h * P * 32;
  const bf16* kh = kbh + (size_t)h * P * 32;
  const bf16* vh = vbh + (size_t)h * P * 32;
  const bf16* T5h = T5 + (size_t)h * 65536;

  const int w = tid >> 6, lane = tid & 63, g = lane >> 4, l15 = lane & 15;

  // stage q (slot-permuted rows, stride 40) and vT (swizzled transpose)
  #pragma unroll
  for (int i = 0; i < 2; ++i) {
    const int flat = i*4096 + tid*8;
    const int pos = flat >> 5, cc = flat & 31;
    const int slot = (pos & 0xE3) | ((pos & 0x04) << 2) | ((pos & 0x18) >> 1);
    bf16x8 qv = *(const bf16x8*)(qh + ((size_t)rb + pos)*32 + cc);
    *(bf16x8*)(qs + slot*40 + cc) = qv;
    bf16x8 vv = *(const bf16x8*)(vh + ((size_t)rb + pos)*32 + cc);
    #pragma unroll
    for (int j = 0; j < 8; ++j) {
      const int row = cc + j;
      const int a = row >> 3;
      const int X = (a << 5) | ((a >> 1) << 4);
      vT[row*264 + (pos ^ X)] = vv[j];
    }
  }

  // prefetch both q-tiles' k-row B-fragments (global, independent of LDS)
  bf16x8 bq0 = *(const bf16x8*)(kh + ((size_t)rb + w*32 +      l15)*32 + 8*g);
  bf16x8 bq1 = *(const bf16x8*)(kh + ((size_t)rb + w*32 + 16 + l15)*32 + 8*g);

  __syncthreads();

  // hoist PV A-fragments from swizzled vT (once per block)
  bf16x8 av[2][8];
  #pragma unroll
  for (int mt = 0; mt < 2; ++mt) {
    const int row = 16*mt + l15;
    const int a = row >> 3;
    const int X = (a << 5) | ((a >> 1) << 4);
    #pragma unroll
    for (int kt = 0; kt < 8; ++kt)
      av[mt][kt] = *(const bf16x8*)(vT + row*264 + ((32*kt + 8*g) ^ X));
  }

  bf16* aoh = aob + (size_t)h * P * 32;
  const f32x4 z = {0.f, 0.f, 0.f, 0.f};

  #pragma unroll
  for (int qt = 0; qt < 2; ++qt) {
    const int q = w*32 + qt*16 + l15;
    const bf16x8 bq = qt ? bq1 : bq0;
    const bf16* Trow = T5h + (size_t)q * 256 + 8*g;
    f32x4 o0a = z, o0b = z, o1a = z, o1b = z;
    float rs = 0.f;
    #pragma unroll
    for (int kt = 0; kt < 8; ++kt) {
      bf16x8 a0 = *(const bf16x8*)(qs + (16*(2*kt + 0) + l15)*40 + 8*g);
      bf16x8 a1 = *(const bf16x8*)(qs + (16*(2*kt + 1) + l15)*40 + 8*g);
      f32x4 s0 = MFMA(a0, bq, z);
      f32x4 s1 = MFMA(a1, bq, z);
      bf16x4 b0 = *(const bf16x4*)(Trow + 32*kt);
      bf16x4 b1 = *(const bf16x4*)(Trow + 32*kt + 4);
      bf16x8 pf;
      #pragma unroll
      for (int r = 0; r < 4; ++r) {
        float e0 = __expf(s0[r] + (float)b0[r]);
        float e1 = __expf(s1[r] + (float)b1[r]);
        pf[r]     = (bf16)e0;
        pf[4 + r] = (bf16)e1;
        rs += e0 + e1;   // unrounded sum (matches f32 reference more closely)
      }
      if (kt & 1) {
        o0b = MFMA(av[0][kt], pf, o0b);
        o1b = MFMA(av[1][kt], pf, o1b);
      } else {
        o0a = MFMA(av[0][kt], pf, o0a);
        o1a = MFMA(av[1][kt], pf, o1a);
      }
    }
    rs += __shfl_xor(rs, 16);
    rs += __shfl_xor(rs, 32);
    const float inv = 1.f / rs;
    bf16x4 p0, p1;
    #pragma unroll
    for (int r = 0; r < 4; ++r) {
      p0[r] = (bf16)((o0a[r] + o0b[r]) * inv);
      p1[r] = (bf16)((o1a[r] + o1b[r]) * inv);
    }
    bf16* dst = aoh + ((size_t)rb + q)*32;
    *(bf16x4*)(dst + 4*g)      = p0;
    *(bf16x4*)(dst + 16 + 4*g) = p1;
  }
}

// ---------------------------------------------------------------------------
// k_gate_out: out = (ao * gate) @ Wo + bo via MFMA; WoF fragment-ordered.
// WoF fragments hoisted + asm-pinned.
// ---------------------------------------------------------------------------
__global__ __launch_bounds__(256) void k_gate_out(
    const bf16* __restrict__ aob, const bf16* __restrict__ gfb,
    const bf16* __restrict__ WoF, const float* __restrict__ bo,
    float* __restrict__ out)
{
  __shared__ bf16 gs[64 * 136];
  const int tid = threadIdx.x;
  const int base = blockIdx.x * 64;
  const int w = tid >> 6, lane = tid & 63, g = lane >> 4, l15 = lane & 15;

  // hoist the wave's 8 WoF A-fragments (mt2 in {0,1} x kt in 0..3)
  f32x4 wf[8];
  #pragma unroll
  for (int j = 0; j < 8; ++j)
    wf[j] = *(const f32x4*)(WoF + ((size_t)((2*w + (j >> 2))*4 + (j & 3))*64 + lane)*8);

  #pragma unroll
  for (int i = 0; i < 4; ++i) {
    const int flat = i*2048 + tid*8;
    const int pos = flat >> 7, c = flat & 127, h = c >> 5;
    bf16x8 a = *(const bf16x8*)(aob + ((size_t)h*P + base + pos)*32 + (c & 31));
    bf16x8 f = *(const bf16x8*)(gfb + ((size_t)(base + pos))*128 + c);
    bf16x8 o;
    #pragma unroll
    for (int j = 0; j < 8; ++j) o[j] = (bf16)((float)a[j] * (float)f[j]);
    *(bf16x8*)(gs + pos*136 + c) = o;
  }

  #pragma unroll
  for (int j = 0; j < 8; ++j)
    asm volatile("" : "+v"(wf[j]));

  __syncthreads();

  const f32x4 z = {0.f, 0.f, 0.f, 0.f};

  for (int nt = 0; nt < 4; ++nt) {
    bf16x8 bfr[4];
    #pragma unroll
    for (int kt = 0; kt < 4; ++kt)
      bfr[kt] = *(const bf16x8*)(gs + (16*nt + l15)*136 + 32*kt + 8*g);
    f32x4 a0 = z, a1 = z;
    #pragma unroll
    for (int kt = 0; kt < 4; ++kt) {
      a0 = MFMA(__builtin_bit_cast(bf16x8, wf[kt]),     bfr[kt], a0);
      a1 = MFMA(__builtin_bit_cast(bf16x8, wf[4 + kt]), bfr[kt], a1);
    }
    const int pos = base + 16*nt + l15;
    {
      const int col = 16*(2*w + 0) + 4*g;
      float4 bb = *(const float4*)(bo + col);
      *(float4*)(out + (size_t)pos*128 + col) =
          make_float4(a0[0] + bb.x, a0[1] + bb.y, a0[2] + bb.z, a0[3] + bb.w);
    }
    {
      const int col = 16*(2*w + 1) + 4*g;
      float4 bb = *(const float4*)(bo + col);
      *(float4*)(out + (size_t)pos*128 + col) =
          make_float4(a1[0] + bb.x, a1[1] + bb.y, a1[2] + bb.z, a1[3] + bb.w);
    }
  }
}

// ---------------------------------------------------------------------------
extern "C" void kernel_launch(void* const* d_in, const int* in_sizes, int n_in,
                              void* d_out, int out_size, void* d_ws, size_t ws_size,
                              hipStream_t stream) {
  const float* pr    = (const float*)d_in[0];
  const float* mask  = (const float*)d_in[1];
  const float* gamma = (const float*)d_in[2];
  const float* beta  = (const float*)d_in[3];
  const float* Wq    = (const float*)d_in[4];
  const float* Wk    = (const float*)d_in[5];
  const float* Wv    = (const float*)d_in[6];
  const float* Wb    = (const float*)d_in[7];
  const float* Wfu   = (const float*)d_in[8];
  const float* bfu   = (const float*)d_in[9];
  const float* Wo    = (const float*)d_in[10];
  const float* bo    = (const float*)d_in[11];
  float* out = (float*)d_out;

  bf16* qbh = (bf16*)d_ws;                        // H*P*32
  bf16* kbh = qbh + (size_t)H * P * 32;
  bf16* vbh = kbh + (size_t)H * P * 32;
  bf16* gfb = vbh + (size_t)H * P * 32;           // P*128
  bf16* aob = gfb + (size_t)P * 128;              // H*P*32
  bf16* T5  = aob + (size_t)H * P * 32;           // H*65536 = H*P
  bf16* WF  = T5  + (size_t)H * P;                // 4*16384
  bf16* WoF = WF  + 4 * 16384;                    // 16384
  bf16* WbF = WoF + 16384;                        // 2048
  float* pb = (float*)(WbF + 2048);               // P*4 fp32

  k_prep<<<41, 256, 0, stream>>>(Wq, Wk, Wv, Wfu, Wo, Wb, WF, WoF, WbF);
  k_ln_proj<<<1024, 256, 0, stream>>>(pr, gamma, beta, bfu, WF, WbF,
                                      qbh, kbh, vbh, gfb, pb);
  k_bias<<<256, 256, 0, stream>>>(mask, pb, T5);
  k_attn<<<1024, 512, 0, stream>>>(qbh, kbh, vbh, T5, aob);
  k_gate_out<<<1024, 256, 0, stream>>>(aob, gfb, WoF, bo, out);
}

// Round 5
// 164.428 us; speedup vs baseline: 1.2354x; 1.0497x over previous
//
#include <hip/hip_runtime.h>
#include <math.h>

#define L 256
#define E 128
#define H 4
#define C 32
#define P (L*L)  // 65536

typedef __bf16 bf16;
typedef __bf16 bf16x8 __attribute__((ext_vector_type(8)));
typedef __bf16 bf16x4 __attribute__((ext_vector_type(4)));
typedef float  f32x4  __attribute__((ext_vector_type(4)));

#define MFMA(a,b,c) __builtin_amdgcn_mfma_f32_16x16x32_bf16((a),(b),(c),0,0,0)

// ---------------------------------------------------------------------------
// k_prep: emit weights in MFMA A-fragment order. Grid 41: blocks 0..39 cover
// (m, frag-quad) with one fragment per wave; block 40 builds WbF.
// frag f=mt*4+kt; elem j at lane (g,l15) is A[row=16mt+l15][k=32kt+8g+j]
// = W[k][row] (*C^-0.5 for Wq). WbF: rows 0..3 = Wb columns, rows 4..15 zero.
// ---------------------------------------------------------------------------
__global__ __launch_bounds__(256) void k_prep(
    const float* __restrict__ Wq, const float* __restrict__ Wk,
    const float* __restrict__ Wv, const float* __restrict__ Wfu,
    const float* __restrict__ Wo, const float* __restrict__ Wb,
    bf16* __restrict__ WF, bf16* __restrict__ WoF, bf16* __restrict__ WbF)
{
  const int b = blockIdx.x;  // 0..40
  const int lane = threadIdx.x & 63, wv = threadIdx.x >> 6;
  const int g = lane >> 4, l15 = lane & 15;
  if (b < 40) {
    const int m = b >> 3;
    const int f = (b & 7) * 4 + wv;
    const float* W = (m==0)?Wq:(m==1)?Wk:(m==2)?Wv:(m==3)?Wfu:Wo;
    bf16* dst = (m < 4) ? (WF + (size_t)m * 16384) : WoF;
    const float sc = (m == 0) ? 0.17677669529663689f : 1.0f;
    const int mt = f >> 2, kt = f & 3;
    const int row = 16*mt + l15, k0 = 32*kt + 8*g;
    bf16x8 o;
    #pragma unroll
    for (int j = 0; j < 8; ++j) o[j] = (bf16)(W[(size_t)(k0+j)*128 + row] * sc);
    *(bf16x8*)(dst + ((size_t)f*64 + lane)*8) = o;
  } else {
    const int kt = wv, k0 = 32*kt + 8*g;
    bf16x8 o;
    #pragma unroll
    for (int j = 0; j < 8; ++j)
      o[j] = (l15 < 4) ? (bf16)Wb[(size_t)(k0+j)*4 + l15] : (bf16)0.0f;
    *(bf16x8*)(WbF + ((size_t)kt*64 + lane)*8) = o;
  }
}

// ---------------------------------------------------------------------------
// k_ln_proj: NOW 512 threads = 8 waves. Wave (m = w&3, half = w>>2) computes
// the half-matrix mt in [4*half, 4*half+4) of matrix m: per-wave pinned
// weight frags drop 32->16 (64 VGPRs), per-wave MFMA chain halves (128->64),
// and waves/SIMD doubles -- attacks the measured latency-bound regime
// (occupancy 12.6%, nothing else saturated, dur flat across 3 weight-path
// variants). Staging read-back stays same-wave-only (each wave reads back
// only its own 64-col half), so no extra barriers.
// q,k,v head-major [h][P][32]; gate [P][128]; pb [P][4] fp32.
// ---------------------------------------------------------------------------
__global__ __launch_bounds__(512) void k_ln_proj(
    const float* __restrict__ pr, const float* __restrict__ gamma,
    const float* __restrict__ beta, const float* __restrict__ bfu,
    const bf16* __restrict__ WF, const bf16* __restrict__ WbF,
    bf16* __restrict__ qbh, bf16* __restrict__ kbh, bf16* __restrict__ vbh,
    bf16* __restrict__ gfb, float* __restrict__ pbo)
{
  __shared__ bf16 xs[64 * 136];        // 17.0 KB
  __shared__ bf16 stag[4][16 * 136];   // 17.0 KB
  const int tid = threadIdx.x;
  const int base = blockIdx.x * 64;
  const int w = tid >> 6, lane = tid & 63, g = lane >> 4, l15 = lane & 15;
  const int m = w & 3, half = w >> 2;

  // --- issue this wave's 16 weight A-fragment loads FIRST; they fly
  //     concurrently with the LN's pr reads ---
  const bf16* WFw = WF + (size_t)m * 16384 + (size_t)half * 8192;
  f32x4 af[16];
  #pragma unroll
  for (int f = 0; f < 16; ++f)
    af[f] = *(const f32x4*)(WFw + ((size_t)f*64 + lane)*8);

  // --- LayerNorm (8 threads per position, 16 floats each) ---
  {
    const int pl = tid >> 3, sub = tid & 7;
    const float4* src = (const float4*)(pr + (size_t)(base + pl) * 128 + sub * 16);
    float4 r[4];
    float s = 0.f, ss = 0.f;
    #pragma unroll
    for (int j = 0; j < 4; ++j) {
      r[j] = src[j];
      s  += r[j].x + r[j].y + r[j].z + r[j].w;
      ss += r[j].x*r[j].x + r[j].y*r[j].y + r[j].z*r[j].z + r[j].w*r[j].w;
    }
    s  += __shfl_xor(s, 1, 8);  s  += __shfl_xor(s, 2, 8);  s  += __shfl_xor(s, 4, 8);
    ss += __shfl_xor(ss, 1, 8); ss += __shfl_xor(ss, 2, 8); ss += __shfl_xor(ss, 4, 8);
    const float mu   = s * 0.0078125f;
    const float var  = ss * 0.0078125f - mu * mu;
    const float rstd = rsqrtf(var + 1e-5f);
    const float4* g4 = (const float4*)(gamma + sub * 16);
    const float4* b4 = (const float4*)(beta + sub * 16);
    bf16* xr = xs + pl * 136 + sub * 16;
    #pragma unroll
    for (int i = 0; i < 2; ++i) {
      float4 r0 = r[2*i], r1 = r[2*i+1];
      float4 gg0 = g4[2*i], gg1 = g4[2*i+1], bb0 = b4[2*i], bb1 = b4[2*i+1];
      bf16x8 o;
      o[0] = (bf16)((r0.x - mu) * rstd * gg0.x + bb0.x);
      o[1] = (bf16)((r0.y - mu) * rstd * gg0.y + bb0.y);
      o[2] = (bf16)((r0.z - mu) * rstd * gg0.z + bb0.z);
      o[3] = (bf16)((r0.w - mu) * rstd * gg0.w + bb0.w);
      o[4] = (bf16)((r1.x - mu) * rstd * gg1.x + bb1.x);
      o[5] = (bf16)((r1.y - mu) * rstd * gg1.y + bb1.y);
      o[6] = (bf16)((r1.z - mu) * rstd * gg1.z + bb1.z);
      o[7] = (bf16)((r1.w - mu) * rstd * gg1.w + bb1.w);
      *(bf16x8*)(xr + 8 * i) = o;
    }
  }

  // --- pin the weight fragments ---
  #pragma unroll
  for (int f = 0; f < 16; ++f)
    asm volatile("" : "+v"(af[f]));

  __syncthreads();

  const f32x4 z = {0.f, 0.f, 0.f, 0.f};

  // --- pair_bias via MFMA: waves 0..3 cover positions base+16w.. ---
  if (w < 4) {
    f32x4 acc = z;
    #pragma unroll
    for (int kt = 0; kt < 4; ++kt) {
      bf16x8 a = *(const bf16x8*)(WbF + ((size_t)kt*64 + lane)*8);
      bf16x8 b = *(const bf16x8*)(xs + (16*w + l15)*136 + 32*kt + 8*g);
      acc = MFMA(a, b, acc);
    }
    if (g == 0)
      *(float4*)(pbo + (size_t)(base + 16*w + l15)*4) =
          make_float4(acc[0], acc[1], acc[2], acc[3]);
  }

  // --- projection: wave (m, half) -> cols [64*half, 64*half+64) of matrix m
  bf16* stw = stag[m];

  for (int nt = 0; nt < 4; ++nt) {
    bf16x8 bfr[4];
    #pragma unroll
    for (int kt = 0; kt < 4; ++kt)
      bfr[kt] = *(const bf16x8*)(xs + (16*nt + l15)*136 + 32*kt + 8*g);
    f32x4 acc[4];
    #pragma unroll
    for (int mtl = 0; mtl < 4; ++mtl) acc[mtl] = z;
    #pragma unroll
    for (int kt = 0; kt < 4; ++kt)
      #pragma unroll
      for (int mtl = 0; mtl < 4; ++mtl)
        acc[mtl] = MFMA(__builtin_bit_cast(bf16x8, af[mtl*4 + kt]), bfr[kt], acc[mtl]);

    // epilogue -> LDS staging (cols 64*half + 16*mtl + 4g, pos l15)
    #pragma unroll
    for (int mtl = 0; mtl < 4; ++mtl) {
      const int col = half*64 + 16*mtl + 4*g;
      f32x4 vv = acc[mtl];
      if (m == 3) {
        float4 bb = *(const float4*)(bfu + col);
        vv[0] = 1.f / (1.f + __expf(-(vv[0] + bb.x)));
        vv[1] = 1.f / (1.f + __expf(-(vv[1] + bb.y)));
        vv[2] = 1.f / (1.f + __expf(-(vv[2] + bb.z)));
        vv[3] = 1.f / (1.f + __expf(-(vv[3] + bb.w)));
      }
      bf16x4 o;
      o[0] = (bf16)vv[0]; o[1] = (bf16)vv[1]; o[2] = (bf16)vv[2]; o[3] = (bf16)vv[3];
      *(bf16x4*)(stw + l15*136 + col) = o;
    }

    // coalesced global store of OWN half (same-wave LDS ordering only)
    #pragma unroll
    for (int i = 0; i < 2; ++i) {
      const int flat = i*512 + lane*8;
      const int p = flat >> 6, cf = half*64 + (flat & 63);
      bf16x8 val = *(const bf16x8*)(stw + p*136 + cf);
      if (m == 3) {
        *(bf16x8*)(gfb + ((size_t)(base + 16*nt + p))*128 + cf) = val;
      } else {
        bf16* dst = (m == 0) ? qbh : (m == 1) ? kbh : vbh;
        const int h = cf >> 5;
        *(bf16x8*)(dst + ((size_t)h*P + base + 16*nt + p)*32 + (cf & 31)) = val;
      }
    }
  }
}

// ---------------------------------------------------------------------------
// k_bias: T5[h][q][v] = mask[q,v] + pb[q,v,h]  (bf16). grid 256 (q), 256 thr.
// ---------------------------------------------------------------------------
__global__ __launch_bounds__(256) void k_bias(
    const float* __restrict__ mask, const float* __restrict__ pb,
    bf16* __restrict__ T5)
{
  const int q = blockIdx.x;
  const int v = threadIdx.x;
  const size_t qv = (size_t)q*256 + v;
  const float m = mask[qv];
  float4 p = *(const float4*)(pb + qv*4);
  T5[qv]            = (bf16)(m + p.x);
  T5[qv +   65536]  = (bf16)(m + p.y);
  T5[qv + 2*65536]  = (bf16)(m + p.z);
  T5[qv + 3*65536]  = (bf16)(m + p.w);
}

// ---------------------------------------------------------------------------
// k_attn: block=(s,h), 512 threads = 8 waves x 32 q-rows (2 q-tiles/wave).
// Swapped QK^T orientation; P lane-local; softmax via 2 shfl_xor on the
// unrounded exp sums; vT swizzle spreads the 4 tid&3 sub-groups onto bank
// offsets {0,16,8,24}; k-row B-frags prefetched; o-accumulators split 2-way.
// ---------------------------------------------------------------------------
__global__ __launch_bounds__(512) void k_attn(
    const bf16* __restrict__ qbh, const bf16* __restrict__ kbh,
    const bf16* __restrict__ vbh, const bf16* __restrict__ T5,
    bf16* __restrict__ aob)
{
  __shared__ bf16 qs[256 * 40];   // 20.0 KB, slot-permuted q-projection
  __shared__ bf16 vT[32 * 264];   // 16.5 KB, swizzled V^T
  const int tid = threadIdx.x;    // 0..511
  const int s = blockIdx.x >> 2, h = blockIdx.x & 3;
  const int rb = s * 256;
  const bf16* qh = qbh + (size_t)h * P * 32;
  const bf16* kh = kbh + (size_t)h * P * 32;
  const bf16* vh = vbh + (size_t)h * P * 32;
  const bf16* T5h = T5 + (size_t)h * 65536;

  const int w = tid >> 6, lane = tid & 63, g = lane >> 4, l15 = lane & 15;

  // stage q (slot-permuted rows, stride 40) and vT (swizzled transpose)
  #pragma unroll
  for (int i = 0; i < 2; ++i) {
    const int flat = i*4096 + tid*8;
    const int pos = flat >> 5, cc = flat & 31;
    const int slot = (pos & 0xE3) | ((pos & 0x04) << 2) | ((pos & 0x18) >> 1);
    bf16x8 qv = *(const bf16x8*)(qh + ((size_t)rb + pos)*32 + cc);
    *(bf16x8*)(qs + slot*40 + cc) = qv;
    bf16x8 vv = *(const bf16x8*)(vh + ((size_t)rb + pos)*32 + cc);
    #pragma unroll
    for (int j = 0; j < 8; ++j) {
      const int row = cc + j;
      const int a = row >> 3;
      const int X = (a << 5) | ((a >> 1) << 4);
      vT[row*264 + (pos ^ X)] = vv[j];
    }
  }

  // prefetch both q-tiles' k-row B-fragments (global, independent of LDS)
  bf16x8 bq0 = *(const bf16x8*)(kh + ((size_t)rb + w*32 +      l15)*32 + 8*g);
  bf16x8 bq1 = *(const bf16x8*)(kh + ((size_t)rb + w*32 + 16 + l15)*32 + 8*g);

  __syncthreads();

  // hoist PV A-fragments from swizzled vT (once per block)
  bf16x8 av[2][8];
  #pragma unroll
  for (int mt = 0; mt < 2; ++mt) {
    const int row = 16*mt + l15;
    const int a = row >> 3;
    const int X = (a << 5) | ((a >> 1) << 4);
    #pragma unroll
    for (int kt = 0; kt < 8; ++kt)
      av[mt][kt] = *(const bf16x8*)(vT + row*264 + ((32*kt + 8*g) ^ X));
  }

  bf16* aoh = aob + (size_t)h * P * 32;
  const f32x4 z = {0.f, 0.f, 0.f, 0.f};

  #pragma unroll
  for (int qt = 0; qt < 2; ++qt) {
    const int q = w*32 + qt*16 + l15;
    const bf16x8 bq = qt ? bq1 : bq0;
    const bf16* Trow = T5h + (size_t)q * 256 + 8*g;
    f32x4 o0a = z, o0b = z, o1a = z, o1b = z;
    float rs = 0.f;
    #pragma unroll
    for (int kt = 0; kt < 8; ++kt) {
      bf16x8 a0 = *(const bf16x8*)(qs + (16*(2*kt + 0) + l15)*40 + 8*g);
      bf16x8 a1 = *(const bf16x8*)(qs + (16*(2*kt + 1) + l15)*40 + 8*g);
      f32x4 s0 = MFMA(a0, bq, z);
      f32x4 s1 = MFMA(a1, bq, z);
      bf16x4 b0 = *(const bf16x4*)(Trow + 32*kt);
      bf16x4 b1 = *(const bf16x4*)(Trow + 32*kt + 4);
      bf16x8 pf;
      #pragma unroll
      for (int r = 0; r < 4; ++r) {
        float e0 = __expf(s0[r] + (float)b0[r]);
        float e1 = __expf(s1[r] + (float)b1[r]);
        pf[r]     = (bf16)e0;
        pf[4 + r] = (bf16)e1;
        rs += e0 + e1;   // unrounded sum (matches f32 reference more closely)
      }
      if (kt & 1) {
        o0b = MFMA(av[0][kt], pf, o0b);
        o1b = MFMA(av[1][kt], pf, o1b);
      } else {
        o0a = MFMA(av[0][kt], pf, o0a);
        o1a = MFMA(av[1][kt], pf, o1a);
      }
    }
    rs += __shfl_xor(rs, 16);
    rs += __shfl_xor(rs, 32);
    const float inv = 1.f / rs;
    bf16x4 p0, p1;
    #pragma unroll
    for (int r = 0; r < 4; ++r) {
      p0[r] = (bf16)((o0a[r] + o0b[r]) * inv);
      p1[r] = (bf16)((o1a[r] + o1b[r]) * inv);
    }
    bf16* dst = aoh + ((size_t)rb + q)*32;
    *(bf16x4*)(dst + 4*g)      = p0;
    *(bf16x4*)(dst + 16 + 4*g) = p1;
  }
}

// ---------------------------------------------------------------------------
// k_gate_out: NOW 512 threads = 8 waves; wave j owns one 16-col output group
// (4 WoF frags = 16 regs, hoisted+pinned); per-wave MFMA chain 32->16.
// ---------------------------------------------------------------------------
__global__ __launch_bounds__(512) void k_gate_out(
    const bf16* __restrict__ aob, const bf16* __restrict__ gfb,
    const bf16* __restrict__ WoF, const float* __restrict__ bo,
    float* __restrict__ out)
{
  __shared__ bf16 gs[64 * 136];
  const int tid = threadIdx.x;
  const int base = blockIdx.x * 64;
  const int w = tid >> 6, lane = tid & 63, g = lane >> 4, l15 = lane & 15;

  // hoist the wave's 4 WoF A-fragments (col group w, kt 0..3)
  f32x4 wf[4];
  #pragma unroll
  for (int kt = 0; kt < 4; ++kt)
    wf[kt] = *(const f32x4*)(WoF + ((size_t)(w*4 + kt)*64 + lane)*8);

  #pragma unroll
  for (int i = 0; i < 2; ++i) {
    const int flat = i*4096 + tid*8;
    const int pos = flat >> 7, c = flat & 127, h = c >> 5;
    bf16x8 a = *(const bf16x8*)(aob + ((size_t)h*P + base + pos)*32 + (c & 31));
    bf16x8 f = *(const bf16x8*)(gfb + ((size_t)(base + pos))*128 + c);
    bf16x8 o;
    #pragma unroll
    for (int j = 0; j < 8; ++j) o[j] = (bf16)((float)a[j] * (float)f[j]);
    *(bf16x8*)(gs + pos*136 + c) = o;
  }

  #pragma unroll
  for (int kt = 0; kt < 4; ++kt)
    asm volatile("" : "+v"(wf[kt]));

  __syncthreads();

  const f32x4 z = {0.f, 0.f, 0.f, 0.f};
  const int col = 16*w + 4*g;
  const float4 bb = *(const float4*)(bo + col);

  for (int nt = 0; nt < 4; ++nt) {
    bf16x8 bfr[4];
    #pragma unroll
    for (int kt = 0; kt < 4; ++kt)
      bfr[kt] = *(const bf16x8*)(gs + (16*nt + l15)*136 + 32*kt + 8*g);
    f32x4 a0 = z;
    #pragma unroll
    for (int kt = 0; kt < 4; ++kt)
      a0 = MFMA(__builtin_bit_cast(bf16x8, wf[kt]), bfr[kt], a0);
    const int pos = base + 16*nt + l15;
    *(float4*)(out + (size_t)pos*128 + col) =
        make_float4(a0[0] + bb.x, a0[1] + bb.y, a0[2] + bb.z, a0[3] + bb.w);
  }
}

// ---------------------------------------------------------------------------
extern "C" void kernel_launch(void* const* d_in, const int* in_sizes, int n_in,
                              void* d_out, int out_size, void* d_ws, size_t ws_size,
                              hipStream_t stream) {
  const float* pr    = (const float*)d_in[0];
  const float* mask  = (const float*)d_in[1];
  const float* gamma = (const float*)d_in[2];
  const float* beta  = (const float*)d_in[3];
  const float* Wq    = (const float*)d_in[4];
  const float* Wk    = (const float*)d_in[5];
  const float* Wv    = (const float*)d_in[6];
  const float* Wb    = (const float*)d_in[7];
  const float* Wfu   = (const float*)d_in[8];
  const float* bfu   = (const float*)d_in[9];
  const float* Wo    = (const float*)d_in[10];
  const float* bo    = (const float*)d_in[11];
  float* out = (float*)d_out;

  bf16* qbh = (bf16*)d_ws;                        // H*P*32
  bf16* kbh = qbh + (size_t)H * P * 32;
  bf16* vbh = kbh + (size_t)H * P * 32;
  bf16* gfb = vbh + (size_t)H * P * 32;           // P*128
  bf16* aob = gfb + (size_t)P * 128;              // H*P*32
  bf16* T5  = aob + (size_t)H * P * 32;           // H*65536 = H*P
  bf16* WF  = T5  + (size_t)H * P;                // 4*16384
  bf16* WoF = WF  + 4 * 16384;                    // 16384
  bf16* WbF = WoF + 16384;                        // 2048
  float* pb = (float*)(WbF + 2048);               // P*4 fp32

  k_prep<<<41, 256, 0, stream>>>(Wq, Wk, Wv, Wfu, Wo, Wb, WF, WoF, WbF);
  k_ln_proj<<<1024, 512, 0, stream>>>(pr, gamma, beta, bfu, WF, WbF,
                                      qbh, kbh, vbh, gfb, pb);
  k_bias<<<256, 256, 0, stream>>>(mask, pb, T5);
  k_attn<<<1024, 512, 0, stream>>>(qbh, kbh, vbh, T5, aob);
  k_gate_out<<<1024, 512, 0, stream>>>(aob, gfb, WoF, bo, out);
}